// Round 13
// baseline (929.789 us; speedup 1.0000x reference)
//
#include <hip/hip_runtime.h>
#include <math.h>

#define LSEQ 2048
#define NB 8
#define NCH 64
#define NTOT (NB*NCH*LSEQ)   // 1048576
#define NROWS (NB*NCH)       // 512

typedef __attribute__((ext_vector_type(8))) short short8;
typedef __attribute__((ext_vector_type(4))) float float4v;

__device__ __forceinline__ float geluf(float x){
    return 0.5f*x*(1.0f+erff(x*0.70710678118654752f));
}
__device__ __forceinline__ float siluf(float x){
    return x/(1.0f+expf(-x));
}
__device__ __forceinline__ float sigf(float x){
    return 1.0f/(1.0f+expf(-x));
}
__device__ __forceinline__ unsigned short f2bf(float f){
    unsigned u=__float_as_uint(f);
    u += 0x7fffu + ((u>>16)&1u);
    return (unsigned short)(u>>16);
}
__device__ __forceinline__ float bf2f(unsigned h){
    return __uint_as_float((h&0xffffu)<<16);
}

// ---------------- weight transpose: w[64][64][3] -> wt[192][64] (gate) ------
__global__ __launch_bounds__(256) void wtrans_kernel(const float* __restrict__ w,
                                                     float* __restrict__ wt){
    int idx = blockIdx.x*256 + threadIdx.x;   // 12288 total
    int j = idx >> 6, co = idx & 63;
    wt[idx] = w[co*192 + j];
}

// ---- ode weight split-prep: WB[lvl][st][hl][tap][co][ci] bf16 --------------
__global__ __launch_bounds__(256) void wprep_kernel(const float* __restrict__ c1w,
                                                    const float* __restrict__ c2w,
                                                    short* __restrict__ WB){
    int idx = blockIdx.x*256 + threadIdx.x;   // 4*2*3*64*64 = 196608
    if (idx >= 196608) return;
    int ci  = idx & 63;
    int co  = (idx>>6) & 63;
    int tap = (idx>>12) % 3;
    int st  = (idx/(3<<12)) & 1;
    int lvl = idx/(6<<12);
    const float* src = (st==0? c1w : c2w);
    float w = src[(size_t)lvl*12288 + co*192 + ci*3 + tap];
    unsigned short hi = f2bf(w);
    float lo = w - bf2f(hi);
    size_t base = ((((size_t)(lvl*2+st)*2+0)*3+tap)*64+co)*64+ci;
    size_t basl = ((((size_t)(lvl*2+st)*2+1)*3+tap)*64+co)*64+ci;
    WB[base] = (short)hi;
    WB[basl] = (short)f2bf(lo);
}

// ---------------- stat = mean over L ----------------------------------------
__global__ __launch_bounds__(256) void stat_kernel(const float* __restrict__ in,
                                                   float* __restrict__ stat){
    int r = blockIdx.x, tid = threadIdx.x;
    const float* p = in + (size_t)r*LSEQ;
    float acc = 0.f;
    for (int i=tid;i<LSEQ;i+=256) acc += p[i];
    for (int o=32;o>0;o>>=1) acc += __shfl_down(acc,o,64);
    __shared__ float red[4];
    if ((tid&63)==0) red[tid>>6]=acc;
    __syncthreads();
    if (tid==0) stat[r] = (red[0]+red[1]+red[2]+red[3])*(1.0f/LSEQ);
}

// ---------------- dywan MLP + filters + ortho -------------------------------
__global__ __launch_bounds__(256) void dywan_kernel(
    const float* __restrict__ stat,
    const float* __restrict__ w1, const float* __restrict__ b1,
    const float* __restrict__ wg1, const float* __restrict__ bg1,
    const float* __restrict__ wg2, const float* __restrict__ bg2,
    float* __restrict__ lo_out, float* __restrict__ hi_out,
    float* __restrict__ ortho_out)
{
    __shared__ float st[512];
    __shared__ float h1s[512];
    __shared__ float h2s[1024];
    __shared__ float fs[112];
    int tid = threadIdx.x;
    for (int i=tid;i<512;i+=256) st[i]=stat[i];
    __syncthreads();
    for (int idx=tid; idx<512; idx+=256){
        int b=idx>>6, j=idx&63;
        float acc=b1[j];
        const float* W=w1+j*64;
        for (int i=0;i<64;i++) acc += st[b*64+i]*W[i];
        h1s[idx]=geluf(acc);
    }
    __syncthreads();
    for (int idx=tid; idx<1024; idx+=256){
        int b=idx>>7, j=idx&127;
        float acc=bg1[j];
        const float* W=wg1+j*64;
        for (int i=0;i<64;i++) acc += h1s[b*64+i]*W[i];
        h2s[idx]=geluf(acc);
    }
    __syncthreads();
    if (tid<112){
        int b=tid/14, j=tid-b*14;
        float acc=bg2[j];
        const float* W=wg2+j*128;
        for (int i=0;i<128;i++) acc += h2s[b*128+i]*W[i];
        fs[tid]=acc;
    }
    __syncthreads();
    if (tid<56){
        int b=tid/7, k=tid-b*7;
        lo_out[tid]=fs[b*14+k];
        hi_out[tid]=fs[b*14+7+k];
    }
    if (tid==0){
        float smooth=0.f, shiftsum=0.f, ampsum=0.f;
        for (int b=0;b<8;b++){
            const float* l = fs + b*14;   // lo row
            float prev=0.f, nrm=0.f;
            for (int k=0;k<7;k++){ smooth += fabsf(l[k]-prev); prev=l[k]; nrm += l[k]*l[k]; }
            smooth += fabsf(prev);
            float denom = sqrtf(nrm) + 1e-8f;
            float sabs=0.f, s2=0.f;
            for (int k=0;k<7;k++){ float v=l[k]/denom; sabs+=fabsf(v); s2+=v*v; }
            shiftsum += sabs*sabs;
            ampsum += fabsf(s2-1.0f);
        }
        smooth *= (1.0f/64.0f);
        float shift = 3.0f*shiftsum/(8.0f*49.0f);
        float amp = ampsum*(1.0f/8.0f);
        *ortho_out = 0.01f*(shift+amp) + 0.1f*smooth;
    }
}

// ---------------- per-batch 7-tap filter conv (edge pad) --------------------
__global__ __launch_bounds__(256) void filt_kernel(
    const float* __restrict__ ap, const float* __restrict__ lo,
    const float* __restrict__ hi, float* __restrict__ na,
    float* __restrict__ det)
{
    int r = blockIdx.y, l0 = blockIdx.x*256, tid = threadIdx.x;
    int b = r>>6;
    __shared__ float s[262];
    __shared__ float fl[7], fh[7];
    for (int idx=tid; idx<262; idx+=256){
        int l = l0+idx-3;
        l = min(max(l,0),LSEQ-1);
        s[idx]=ap[(size_t)r*LSEQ+l];
    }
    if (tid<7) fl[tid]=lo[b*7+tid];
    else if (tid<14) fh[tid-7]=hi[b*7+tid-7];
    __syncthreads();
    float a=0.f, d=0.f;
    #pragma unroll
    for (int k=0;k<7;k++){ float v=s[tid+k]; a+=v*fl[k]; d+=v*fh[k]; }
    na[(size_t)r*LSEQ+l0+tid]=a;
    det[(size_t)r*LSEQ+l0+tid]=d;
}

// ---------------- time grid pass1: per-row stats (batched over levels) ------
__global__ __launch_bounds__(256) void tg_pass1(const float* __restrict__ CB,
                                                float* __restrict__ rowstats){
    __shared__ float sh[2048];
    __shared__ float red[28];
    int r = blockIdx.x, lvl = blockIdx.y, tid = threadIdx.x;
    const float* s = CB + (size_t)lvl*NTOT + (size_t)r*LSEQ;
    float* rso = rowstats + (size_t)(lvl*NROWS+r)*8;
    for (int i=tid;i<2048;i+=256) sh[i]=s[i];
    __syncthreads();
    float ssq=0.f;
    for (int i=tid;i<2048;i+=256){ float v=sh[i]; ssq+=v*v; }
    float mn=1e30f, mx=-1e30f, s0=0.f,s1=0.f,s2=0.f,s3=0.f;
    for (int j=tid;j<2047;j+=256){
        int k0 = (j-2>0)? j-2:0;
        int k1 = (j+2<2046)? j+2:2046;
        float acc=0.f;
        for (int k=k0;k<=k1;k++) acc += fabsf(sh[k+1]-sh[k]);
        float inten = acc*0.2f;
        mn=fminf(mn,inten); mx=fmaxf(mx,inten);
        if (j<511)  s0+=inten;
        if (j<1023) s1+=inten;
        if (j<1534) s2+=inten;
        if (j<2046) s3+=inten;
    }
    float vals[7]={mn,mx,s0,s1,s2,s3,ssq};
    for (int o=32;o>0;o>>=1){
        vals[0]=fminf(vals[0],__shfl_down(vals[0],o,64));
        vals[1]=fmaxf(vals[1],__shfl_down(vals[1],o,64));
        vals[2]+=__shfl_down(vals[2],o,64);
        vals[3]+=__shfl_down(vals[3],o,64);
        vals[4]+=__shfl_down(vals[4],o,64);
        vals[5]+=__shfl_down(vals[5],o,64);
        vals[6]+=__shfl_down(vals[6],o,64);
    }
    int lane=tid&63, w=tid>>6;
    if (lane==0) for (int q=0;q<7;q++) red[w*7+q]=vals[q];
    __syncthreads();
    if (tid==0){
        rso[0]=fminf(fminf(red[0],red[7]),fminf(red[14],red[21]));
        rso[1]=fmaxf(fmaxf(red[1],red[8]),fmaxf(red[15],red[22]));
        rso[2]=red[2]+red[9]+red[16]+red[23];
        rso[3]=red[3]+red[10]+red[17]+red[24];
        rso[4]=red[4]+red[11]+red[18]+red[25];
        rso[5]=red[5]+red[12]+red[19]+red[26];
        rso[6]=red[6]+red[13]+red[20]+red[27];
    }
}

// ---------------- time grid finalize + modulation (grid = 4 levels) ---------
__global__ __launch_bounds__(256) void tg_finalize(
    const float* __restrict__ rowstats,
    const float* __restrict__ wt, const float* __restrict__ bt,
    const float* __restrict__ wm, const float* __restrict__ bm,
    const float* __restrict__ emb,
    float* __restrict__ ts_out, float* __restrict__ modsc,
    float* __restrict__ modbi, float* __restrict__ ein,
    float* __restrict__ eout)
{
    int tid=threadIdx.x;
    const int lvl=blockIdx.x;
    const float* rs = rowstats + (size_t)lvl*NROWS*8;
    __shared__ float red[28];
    __shared__ float stv[9];
    __shared__ float temb[144];
    float mn=1e30f,mx=-1e30f,a0=0.f,a1=0.f,a2=0.f,a3=0.f,m3=-1e30f;
    for (int r=tid;r<512;r+=256){
        mn=fminf(mn,rs[r*8+0]); mx=fmaxf(mx,rs[r*8+1]);
        a0+=rs[r*8+2]; a1+=rs[r*8+3]; a2+=rs[r*8+4]; a3+=rs[r*8+5];
        m3=fmaxf(m3,rs[r*8+5]);
    }
    float vals[7]={mn,mx,a0,a1,a2,a3,m3};
    for (int o=32;o>0;o>>=1){
        vals[0]=fminf(vals[0],__shfl_down(vals[0],o,64));
        vals[1]=fmaxf(vals[1],__shfl_down(vals[1],o,64));
        vals[2]+=__shfl_down(vals[2],o,64);
        vals[3]+=__shfl_down(vals[3],o,64);
        vals[4]+=__shfl_down(vals[4],o,64);
        vals[5]+=__shfl_down(vals[5],o,64);
        vals[6]=fmaxf(vals[6],__shfl_down(vals[6],o,64));
    }
    int lane=tid&63, w=tid>>6;
    if (lane==0) for (int q=0;q<7;q++) red[w*7+q]=vals[q];
    if (tid<8){
        float e=0.f;
        for (int c=0;c<64;c++) e += rs[(tid*64+c)*8+6];
        ein[lvl*8+tid]=e*(1.0f/131072.0f);
        eout[lvl*8+tid]=0.f;
    }
    __syncthreads();
    if (tid==0){
        float mnv=fminf(fminf(red[0],red[7]),fminf(red[14],red[21]));
        float mxv=fmaxf(fmaxf(red[1],red[8]),fmaxf(red[15],red[22]));
        float s0=red[2]+red[9]+red[16]+red[23];
        float s1=red[3]+red[10]+red[17]+red[24];
        float s2=red[4]+red[11]+red[18]+red[25];
        float s3=red[5]+red[12]+red[19]+red[26];
        float m3v=fmaxf(fmaxf(red[6],red[13]),fmaxf(red[20],red[27]));
        const float idxs[5]={0.f,511.f,1023.f,1534.f,2046.f};
        float tsv[5];
        if (mxv-mnv < 1e-8f){
            for (int k=0;k<5;k++) tsv[k]=idxs[k]/2046.0f;
        } else {
            float a = 0.9f/(mxv-mnv+1e-30f);
            float bb = 0.1f - a*mnv;
            float gmax = a*m3v + bb*2046.0f;
            float sums[5]={0.f,s0,s1,s2,s3};
            tsv[0]=0.f;
            for (int k=1;k<5;k++)
                tsv[k]=(a*(sums[k]*(1.0f/512.0f)) + bb*idxs[k])/gmax;
        }
        for (int k=0;k<5;k++){ ts_out[lvl*8+k]=tsv[k]; stv[2*k]=tsv[k]; }
        for (int k=0;k<4;k++) stv[2*k+1]=tsv[k] + 0.5f*(tsv[k+1]-tsv[k]);
    }
    __syncthreads();
    if (tid<144){
        int m=tid>>4, i=tid&15;
        float z = wt[lvl*16+i]*stv[m] + bt[lvl*16+i];
        temb[tid]=siluf(z);
    }
    __syncthreads();
    for (int idx=tid; idx<1152; idx+=256){
        int m=idx>>7, c=idx&127;
        float g=bm[lvl*128+c];
        const float* W=wm+(size_t)(lvl*128+c)*16;
        const float* te=temb+m*16;
        for (int i=0;i<16;i++) g += W[i]*te[i];
        if (c<64) modsc[lvl*576+m*64+c]=1.0f+g+emb[(lvl*8+lvl)*64+c];
        else      modbi[lvl*576+m*64+(c-64)]=g;
    }
}

// ---------------- MFMA fused ode_f eval (32-pos tiles, 15.3 KB LDS) ---------
// grid (64, 8, 4): (32-pos tile, batch, level). block 256 = 4 waves.
// conv1: 3-term split (y hi+lo). conv2: 2-term (Whi+Wlo)*h_hi, h stored hi-only.
// k1..k3 and acc live in GLOBAL packed-bf16 pair buffers [lvl][b][ci/2][l].
__global__ __launch_bounds__(256) void ode_eval_all(
    const float* __restrict__ yinB, const unsigned* __restrict__ kprevB,
    unsigned* __restrict__ koutB, unsigned* __restrict__ accB,
    float* __restrict__ youtB,
    const short* __restrict__ WB, const float* __restrict__ c1bB,
    const float* __restrict__ c2bB,
    const float* __restrict__ modscB, const float* __restrict__ modbiB,
    const float* __restrict__ tsB, float* __restrict__ eoutB,
    int step, int eval, int do_energy)
{
    __shared__ unsigned yTh[36][36];   // row r <-> ye pos l0-2+r ; packed ci pairs
    __shared__ unsigned yTl[36][36];
    __shared__ unsigned hTh[34][36];   // row r <-> h pos l0-1+r (hi only)
    __shared__ float red[4];
    const int tid=threadIdx.x;
    const int lvl=blockIdx.z;
    const int b=blockIdx.y;
    const int l0=blockIdx.x*32;
    const size_t loff=(size_t)lvl*NTOT;
    const size_t loffP=(size_t)lvl*(NTOT/2);
    const float* yin = yinB + loff;
    const unsigned* kprev = kprevB + loffP;
    unsigned* kout = koutB + loffP;
    unsigned* acc = accB + loffP;
    float* yout = youtB + loff;
    const float dt = tsB[lvl*8+step+1]-tsB[lvl*8+step];
    const float alpha=(eval==0)?0.f:((eval==3)?dt:0.5f*dt);
    const int tslot=2*step+((eval==0)?0:((eval==3)?2:1));
    const int wv=tid>>6, lane=tid&63;
    const int n=lane&15, quad=lane>>4;
    const int m0=wv*16;

    // ---- stage ye (+alpha*kprev) into split-bf16 transposed tiles ----
    {
        int r = lane;
        if (r < 36){
            int l = l0 - 2 + r;
            bool ok = (l>=0 && l<LSEQ);
            #pragma unroll
            for (int qq=0; qq<8; qq++){
                int q = wv*8 + qq;
                float v0=0.f, v1=0.f;
                if (ok){
                    size_t g0=(size_t)(b*64+2*q)*LSEQ+l;
                    v0=yin[g0]; v1=yin[g0+LSEQ];
                    if (eval!=0){
                        unsigned ku = kprev[((size_t)(b*32+q))*LSEQ + l];
                        v0 += alpha*bf2f(ku);
                        v1 += alpha*bf2f(ku>>16);
                    }
                }
                unsigned short h0=f2bf(v0), h1=f2bf(v1);
                yTh[r][q] = (unsigned)h0 | ((unsigned)h1<<16);
                yTl[r][q] = (unsigned)f2bf(v0-bf2f(h0)) | ((unsigned)f2bf(v1-bf2f(h1))<<16);
            }
        }
    }
    __syncthreads();

    // ---- conv1: h pos l0-1..l0+32 (3 n-tiles; tile 2 only n<2 stored) ----
    {
        const short* W1 = WB + (size_t)(lvl*2+0)*2*3*4096;
        short8 A[3][2][2];
        #pragma unroll
        for (int tap=0;tap<3;tap++)
            #pragma unroll
            for (int ks=0;ks<2;ks++)
                #pragma unroll
                for (int hl=0;hl<2;hl++)
                    A[tap][ks][hl] = *(const short8*)(W1 + (((size_t)hl*3+tap)*64 + (m0+n))*64 + ks*32 + quad*8);
        float bia[4];
        #pragma unroll
        for (int reg=0;reg<4;reg++) bia[reg]=c1bB[lvl*64 + m0 + quad*4 + reg];
        const int q0=(m0>>1)+quad*2;
        for (int nt=0; nt<3; nt++){
            float4v d = {bia[0],bia[1],bia[2],bia[3]};
            #pragma unroll
            for (int tap=0;tap<3;tap++){
                int rr = 16*nt + n + tap;
                rr = (rr>35)? 35 : rr;           // clamp (junk rows unused)
                const unsigned* ph=&yTh[rr][0];
                const unsigned* pl=&yTl[rr][0];
                #pragma unroll
                for (int ks=0;ks<2;ks++){
                    short8 bh = *(const short8*)(ph + ks*16 + quad*4);
                    short8 bl = *(const short8*)(pl + ks*16 + quad*4);
                    d = __builtin_amdgcn_mfma_f32_16x16x32_bf16(A[tap][ks][0], bh, d, 0,0,0);
                    d = __builtin_amdgcn_mfma_f32_16x16x32_bf16(A[tap][ks][0], bl, d, 0,0,0);
                    d = __builtin_amdgcn_mfma_f32_16x16x32_bf16(A[tap][ks][1], bh, d, 0,0,0);
                }
            }
            if (nt<2 || n<2){
                int rh = 16*nt + n;
                int hpos = l0 - 1 + rh;
                bool okh = (hpos>=0 && hpos<LSEQ);
                float h0 = okh? geluf(d[0]) : 0.f;
                float h1 = okh? geluf(d[1]) : 0.f;
                float h2 = okh? geluf(d[2]) : 0.f;
                float h3 = okh? geluf(d[3]) : 0.f;
                hTh[rh][q0]   = (unsigned)f2bf(h0) | ((unsigned)f2bf(h1)<<16);
                hTh[rh][q0+1] = (unsigned)f2bf(h2) | ((unsigned)f2bf(h3)<<16);
            }
        }
    }
    __syncthreads();

    // ---- conv2 (2 n-tiles, output pos l0..l0+31) + packed epilogue ----
    float esum=0.f;
    {
        const short* W2 = WB + (size_t)(lvl*2+1)*2*3*4096;
        short8 A[3][2][2];
        #pragma unroll
        for (int tap=0;tap<3;tap++)
            #pragma unroll
            for (int ks=0;ks<2;ks++)
                #pragma unroll
                for (int hl=0;hl<2;hl++)
                    A[tap][ks][hl] = *(const short8*)(W2 + (((size_t)hl*3+tap)*64 + (m0+n))*64 + ks*32 + quad*8);
        float bib[4], sc[4], bi2[4];
        #pragma unroll
        for (int reg=0;reg<4;reg++){
            int co = m0 + quad*4 + reg;
            bib[reg]=c2bB[lvl*64+co];
            sc[reg]=modscB[lvl*576+tslot*64+co];
            bi2[reg]=modbiB[lvl*576+tslot*64+co];
        }
        const float dt6 = dt/6.0f;
        const int qy0=(m0+quad*4)>>1;
        for (int nt=0; nt<2; nt++){
            float4v d = {bib[0],bib[1],bib[2],bib[3]};
            #pragma unroll
            for (int tap=0;tap<3;tap++){
                const int rr = 16*nt + n + tap;
                const unsigned* ph=&hTh[rr][0];
                #pragma unroll
                for (int ks=0;ks<2;ks++){
                    short8 bh = *(const short8*)(ph + ks*16 + quad*4);
                    d = __builtin_amdgcn_mfma_f32_16x16x32_bf16(A[tap][ks][0], bh, d, 0,0,0);
                    d = __builtin_amdgcn_mfma_f32_16x16x32_bf16(A[tap][ks][1], bh, d, 0,0,0);
                }
            }
            int p = l0 + 16*nt + n;
            int ry = 16*nt + n + 2;
            unsigned uh0=yTh[ry][qy0],   ul0=yTl[ry][qy0];
            unsigned uh1=yTh[ry][qy0+1], ul1=yTl[ry][qy0+1];
            float yev[4];
            yev[0]=bf2f(uh0)+bf2f(ul0);
            yev[1]=bf2f(uh0>>16)+bf2f(ul0>>16);
            yev[2]=bf2f(uh1)+bf2f(ul1);
            yev[3]=bf2f(uh1>>16)+bf2f(ul1>>16);
            float kv[4];
            #pragma unroll
            for (int reg=0;reg<4;reg++){
                float m = d[reg]*sc[reg] + bi2[reg];
                kv[reg] = siluf(m) - 0.1f*yev[reg];
            }
            size_t ia = ((size_t)(b*32+qy0))*LSEQ + p;
            size_t ib = ia + LSEQ;
            if (eval==0){
                unsigned ka=(unsigned)f2bf(kv[0])|((unsigned)f2bf(kv[1])<<16);
                unsigned kb=(unsigned)f2bf(kv[2])|((unsigned)f2bf(kv[3])<<16);
                kout[ia]=ka; kout[ib]=kb;
                acc[ia]=ka;  acc[ib]=kb;
            } else if (eval<3){
                unsigned ka=(unsigned)f2bf(kv[0])|((unsigned)f2bf(kv[1])<<16);
                unsigned kb=(unsigned)f2bf(kv[2])|((unsigned)f2bf(kv[3])<<16);
                kout[ia]=ka; kout[ib]=kb;
                unsigned ua=acc[ia], ub=acc[ib];
                float a0=bf2f(ua)+2.f*kv[0],     a1=bf2f(ua>>16)+2.f*kv[1];
                float a2=bf2f(ub)+2.f*kv[2],     a3=bf2f(ub>>16)+2.f*kv[3];
                acc[ia]=(unsigned)f2bf(a0)|((unsigned)f2bf(a1)<<16);
                acc[ib]=(unsigned)f2bf(a2)|((unsigned)f2bf(a3)<<16);
            } else {
                unsigned ua=acc[ia], ub=acc[ib];
                float av[4]={bf2f(ua),bf2f(ua>>16),bf2f(ub),bf2f(ub>>16)};
                size_t gbase=(size_t)(b*64 + m0 + quad*4)*LSEQ + p;
                #pragma unroll
                for (int reg=0;reg<4;reg++){
                    size_t gi = gbase + (size_t)reg*LSEQ;
                    float yn = yin[gi] + dt6*(av[reg]+kv[reg]);
                    yout[gi]=yn;
                    esum += yn*yn;
                }
            }
        }
    }
    if (do_energy){
        for (int o=32;o>0;o>>=1) esum+=__shfl_down(esum,o,64);
        if ((tid&63)==0) red[tid>>6]=esum;
        __syncthreads();
        if (tid==0) atomicAdd(&eoutB[lvl*8+b], red[0]+red[1]+red[2]+red[3]);
    }
}

// ---------------- energy renorm (batched over levels) -----------------------
__global__ __launch_bounds__(256) void scale_kernel(
    const float* __restrict__ y, const float* __restrict__ ein,
    const float* __restrict__ eout, float* __restrict__ o)
{
    int idx = blockIdx.x*256 + threadIdx.x;
    int lb = idx>>17;   // (lvl*8+b), 131072 elems each
    float eo = eout[lb]*(1.0f/131072.0f);
    o[idx] = y[idx]*sqrtf(ein[lb]/(eo+1e-8f));
}

// ---------------- fused reconstruction: [attn] + gate + residual ------------
// grid (32, NB). detail modified in LDS and (if attn) written back to out.
__global__ __launch_bounds__(256) void recon_kernel(
    const float* __restrict__ cur, float* __restrict__ detail,
    const float* __restrict__ a1w, const float* __restrict__ a1b,
    const float* __restrict__ a2w, const float* __restrict__ a2b,
    const float* __restrict__ gwt, const float* __restrict__ gb,
    float* __restrict__ curout, int has_attn)
{
    __shared__ float yc[64][66];
    __shared__ float dtile[64][65];
    __shared__ float hid[16][64];
    const int tid=threadIdx.x, b=blockIdx.y, l0=blockIdx.x*64;
    for (int idx=tid; idx<64*66; idx+=256){
        int ci=idx/66, u=idx-ci*66;
        int l=l0+u-1;
        yc[ci][u]=(l>=0 && l<LSEQ)? cur[(size_t)(b*64+ci)*LSEQ+l] : 0.f;
    }
    for (int idx=tid; idx<4096; idx+=256){
        int ci=idx>>6, p=idx&63;
        dtile[ci][p]=detail[(size_t)(b*64+ci)*LSEQ+l0+p];
    }
    __syncthreads();
    if (has_attn){
        for (int idx=tid; idx<1024; idx+=256){
            int h=idx>>6, p=idx&63;
            float acc=a1b[h];
            const float* W=a1w+h*64;
            for (int ci=0;ci<64;ci++) acc += W[ci]*yc[ci][p+1];
            hid[h][p]=geluf(acc);
        }
        __syncthreads();
        for (int idx=tid; idx<4096; idx+=256){
            int co=idx>>6, p=idx&63;
            float acc=a2b[co];
            const float* W=a2w+co*16;
            #pragma unroll
            for (int h=0;h<16;h++) acc += W[h]*hid[h][p];
            float a=sigf(acc);
            float dnew = dtile[co][p]*(1.0f+a);
            dtile[co][p]=dnew;
            detail[(size_t)(b*64+co)*LSEQ+l0+p]=dnew;
        }
        __syncthreads();
    }
    const int co=tid&63, g=tid>>6;
    const int p0=g*16;
    float a[16];
    float bb=gb[co];
    #pragma unroll
    for (int i=0;i<16;i++) a[i]=bb;
    for (int ci=0;ci<64;ci++){
        float w0=gwt[(ci*3+0)*64+co];
        float w1_=gwt[(ci*3+1)*64+co];
        float w2_=gwt[(ci*3+2)*64+co];
        float x[18];
        #pragma unroll
        for (int j=0;j<18;j++) x[j]=yc[ci][p0+j];
        #pragma unroll
        for (int i=0;i<16;i++) a[i] += w0*x[i]+w1_*x[i+1]+w2_*x[i+2];
    }
    float r[16];
    #pragma unroll
    for (int i=0;i<16;i++){
        float gt=sigf(a[i]);
        r[i]=yc[co][p0+i+1]+gt*dtile[co][p0+i];
    }
    __syncthreads();
    #pragma unroll
    for (int i=0;i<16;i++) dtile[co][p0+i]=r[i];
    __syncthreads();
    for (int idx=tid; idx<4096; idx+=256){
        int ci=idx>>6, p=idx&63;
        curout[(size_t)(b*64+ci)*LSEQ+l0+p]=dtile[ci][p];
    }
}

extern "C" void kernel_launch(void* const* d_in, const int* in_sizes, int n_in,
                              void* d_out, int out_size, void* d_ws, size_t ws_size,
                              hipStream_t stream)
{
    (void)in_sizes; (void)n_in; (void)out_size; (void)ws_size;
    const float* x       =(const float*)d_in[0];
    const float* dy_w1   =(const float*)d_in[1];
    const float* dy_b1   =(const float*)d_in[2];
    const float* dy_wg1  =(const float*)d_in[3];
    const float* dy_bg1  =(const float*)d_in[4];
    const float* dy_wg2  =(const float*)d_in[5];
    const float* dy_bg2  =(const float*)d_in[6];
    const float* ode_c1w =(const float*)d_in[7];
    const float* ode_c1b =(const float*)d_in[8];
    const float* ode_c2w =(const float*)d_in[9];
    const float* ode_c2b =(const float*)d_in[10];
    const float* ode_wt  =(const float*)d_in[11];
    const float* ode_bt  =(const float*)d_in[12];
    const float* ode_wm  =(const float*)d_in[13];
    const float* ode_bm  =(const float*)d_in[14];
    const float* ode_emb =(const float*)d_in[15];
    const float* gate_w  =(const float*)d_in[16];
    const float* gate_b  =(const float*)d_in[17];
    const float* attn1_w =(const float*)d_in[18];
    const float* attn1_b =(const float*)d_in[19];
    const float* attn2_w =(const float*)d_in[20];
    const float* attn2_b =(const float*)d_in[21];
    float* out=(float*)d_out;
    float* ws=(float*)d_ws;
    const size_t N=NTOT;
    // workspace layout (floats)
    float* CB = ws;                      // coeff[4]: A0, D1, D2, D3 (4N)
    float* PB = ws+4*N;                  // y ping (4 levels) — also decomp temps
    float* QB = ws+8*N;                  // y pong (4 levels)
    unsigned* K0P=(unsigned*)(ws+12*N);  // packed-bf16 k ping (2N floats)
    unsigned* K1P=(unsigned*)(ws+14*N);  // packed-bf16 k pong
    unsigned* ACP=(unsigned*)(ws+16*N);  // packed-bf16 acc
    float* SM = ws+20*N;
    float* stat_ws =SM;          // 512
    float* lo_ws   =SM+512;      // 64
    float* hi_ws   =SM+576;      // 64
    float* rowstats=SM+1024;     // 4*512*8 = 16384
    float* ts_ws   =SM+17408;    // 4*8
    float* modsc   =SM+17536;    // 4*576
    float* modbi   =SM+19840;    // 4*576
    float* ein     =SM+22144;    // 32
    float* eoutb   =SM+22176;    // 32
    short* WB      =(short*)(SM+24576);  // 393216 bf16 = 196608 floats
    float* WTG     =SM+24576+196608;     // 3*12288 (gate weights, transposed)

    dim3 blk(256);

    wprep_kernel<<<768,blk,0,stream>>>(ode_c1w, ode_c2w, WB);
    for (int i=0;i<3;i++)
        wtrans_kernel<<<48,blk,0,stream>>>(gate_w+(size_t)i*12288, WTG+(size_t)i*12288);

    // ---- wavelet decomposition (3 levels, sequential) ----
    const float* cura=x;
    float* outsA[3]={PB, PB+N, CB};      // T0, T1, A0-final
    float* outsD[3]={CB+N, CB+2*N, CB+3*N};
    for (int lv=0; lv<3; lv++){
        stat_kernel<<<NROWS,blk,0,stream>>>(cura, stat_ws);
        dywan_kernel<<<1,blk,0,stream>>>(stat_ws, dy_w1,dy_b1,dy_wg1,dy_bg1,dy_wg2,dy_bg2,
                                         lo_ws, hi_ws, out+4*N);
        filt_kernel<<<dim3(8,NROWS),blk,0,stream>>>(cura, lo_ws, hi_ws, outsA[lv], outsD[lv]);
        cura=outsA[lv];
    }

    // ---- adaptive grids + modulation for all 4 levels ----
    tg_pass1<<<dim3(NROWS,4),blk,0,stream>>>(CB, rowstats);
    tg_finalize<<<4,blk,0,stream>>>(rowstats, ode_wt, ode_bt, ode_wm, ode_bm,
                                    ode_emb, ts_ws, modsc, modbi, ein, eoutb);

    // ---- RK4: 16 evals, each batched over 4 levels ----
    const float* yins[4]={CB, PB, QB, PB};
    float*       youts[4]={PB, QB, PB, QB};
    for (int step=0;step<4;step++){
        for (int ev=0;ev<4;ev++){
            const unsigned* kp=(ev==2)? K1P : K0P;
            unsigned* ko=(ev==1)? K1P : K0P;
            int doe=(step==3 && ev==3)?1:0;
            ode_eval_all<<<dim3(64,NB,4),blk,0,stream>>>(
                yins[step],kp,ko,ACP,youts[step],
                WB,ode_c1b,ode_c2b,modsc,modbi,ts_ws,eoutb,step,ev,doe);
        }
    }
    scale_kernel<<<4*NTOT/256,blk,0,stream>>>(QB, ein, eoutb, out);

    // ---- reconstruction (fused attn+gate) ----
    // i=2: no attn; current: out0 -> PB; detail = out slot 3
    recon_kernel<<<dim3(32,NB),blk,0,stream>>>(out+0*N, out+3*N,
        attn1_w, attn1_b, attn2_w, attn2_b,
        WTG+2*12288, gate_b+128, PB, 0);
    // i=1: attn (set 1) on out slot 2, then gate: PB -> QB
    recon_kernel<<<dim3(32,NB),blk,0,stream>>>(PB, out+2*N,
        attn1_w+1024, attn1_b+16, attn2_w+1024, attn2_b+64,
        WTG+1*12288, gate_b+64, QB, 1);
    // i=0: attn (set 0) on out slot 1, then gate: QB -> out slot 0
    recon_kernel<<<dim3(32,NB),blk,0,stream>>>(QB, out+1*N,
        attn1_w, attn1_b, attn2_w, attn2_b,
        WTG, gate_b, out+0*N, 1);
}

// Round 14
// 751.208 us; speedup vs baseline: 1.2377x; 1.2377x over previous
//
#include <hip/hip_runtime.h>
#include <math.h>

#define LSEQ 2048
#define NB 8
#define NCH 64
#define NTOT (NB*NCH*LSEQ)   // 1048576
#define NROWS (NB*NCH)       // 512

typedef __attribute__((ext_vector_type(8))) short short8;
typedef __attribute__((ext_vector_type(4))) float float4v;

__device__ __forceinline__ float geluf(float x){
    return 0.5f*x*(1.0f+erff(x*0.70710678118654752f));
}
__device__ __forceinline__ float siluf(float x){
    return x/(1.0f+expf(-x));
}
__device__ __forceinline__ float sigf(float x){
    return 1.0f/(1.0f+expf(-x));
}
__device__ __forceinline__ unsigned short f2bf(float f){
    unsigned u=__float_as_uint(f);
    u += 0x7fffu + ((u>>16)&1u);
    return (unsigned short)(u>>16);
}
__device__ __forceinline__ float bf2f(unsigned h){
    return __uint_as_float((h&0xffffu)<<16);
}

// ---------------- weight transpose: w[64][64][3] -> wt[192][64] (gate) ------
__global__ __launch_bounds__(256) void wtrans_kernel(const float* __restrict__ w,
                                                     float* __restrict__ wt){
    int idx = blockIdx.x*256 + threadIdx.x;   // 12288 total
    int j = idx >> 6, co = idx & 63;
    wt[idx] = w[co*192 + j];
}

// ---- ode weight split-prep: WB[lvl][st][hl][tap][co][ci] bf16 --------------
__global__ __launch_bounds__(256) void wprep_kernel(const float* __restrict__ c1w,
                                                    const float* __restrict__ c2w,
                                                    short* __restrict__ WB){
    int idx = blockIdx.x*256 + threadIdx.x;   // 4*2*3*64*64 = 196608
    if (idx >= 196608) return;
    int ci  = idx & 63;
    int co  = (idx>>6) & 63;
    int tap = (idx>>12) % 3;
    int st  = (idx/(3<<12)) & 1;
    int lvl = idx/(6<<12);
    const float* src = (st==0? c1w : c2w);
    float w = src[(size_t)lvl*12288 + co*192 + ci*3 + tap];
    unsigned short hi = f2bf(w);
    float lo = w - bf2f(hi);
    size_t base = ((((size_t)(lvl*2+st)*2+0)*3+tap)*64+co)*64+ci;
    size_t basl = ((((size_t)(lvl*2+st)*2+1)*3+tap)*64+co)*64+ci;
    WB[base] = (short)hi;
    WB[basl] = (short)f2bf(lo);
}

// ---------------- stat = ROW SUMS over L (dywan normalizes) -----------------
__global__ __launch_bounds__(256) void stat_kernel(const float* __restrict__ in,
                                                   float* __restrict__ stat){
    int r = blockIdx.x, tid = threadIdx.x;
    const float* p = in + (size_t)r*LSEQ;
    float acc = 0.f;
    for (int i=tid;i<LSEQ;i+=256) acc += p[i];
    for (int o=32;o>0;o>>=1) acc += __shfl_down(acc,o,64);
    __shared__ float red[4];
    if ((tid&63)==0) red[tid>>6]=acc;
    __syncthreads();
    if (tid==0) stat[r] = red[0]+red[1]+red[2]+red[3];
}

// ---------------- dywan MLP + filters + ortho (stat = raw sums) -------------
__global__ __launch_bounds__(256) void dywan_kernel(
    float* __restrict__ stat,
    const float* __restrict__ w1, const float* __restrict__ b1,
    const float* __restrict__ wg1, const float* __restrict__ bg1,
    const float* __restrict__ wg2, const float* __restrict__ bg2,
    float* __restrict__ lo_out, float* __restrict__ hi_out,
    float* __restrict__ ortho_out)
{
    __shared__ float st[512];
    __shared__ float h1s[512];
    __shared__ float h2s[1024];
    __shared__ float fs[112];
    int tid = threadIdx.x;
    for (int i=tid;i<512;i+=256) st[i]=stat[i]*(1.0f/LSEQ);
    __syncthreads();
    // reset stat accumulator for the next level's filt atomics
    for (int i=tid;i<512;i+=256) stat[i]=0.f;
    for (int idx=tid; idx<512; idx+=256){
        int b=idx>>6, j=idx&63;
        float acc=b1[j];
        const float* W=w1+j*64;
        for (int i=0;i<64;i++) acc += st[b*64+i]*W[i];
        h1s[idx]=geluf(acc);
    }
    __syncthreads();
    for (int idx=tid; idx<1024; idx+=256){
        int b=idx>>7, j=idx&127;
        float acc=bg1[j];
        const float* W=wg1+j*64;
        for (int i=0;i<64;i++) acc += h1s[b*64+i]*W[i];
        h2s[idx]=geluf(acc);
    }
    __syncthreads();
    if (tid<112){
        int b=tid/14, j=tid-b*14;
        float acc=bg2[j];
        const float* W=wg2+j*128;
        for (int i=0;i<128;i++) acc += h2s[b*128+i]*W[i];
        fs[tid]=acc;
    }
    __syncthreads();
    if (tid<56){
        int b=tid/7, k=tid-b*7;
        lo_out[tid]=fs[b*14+k];
        hi_out[tid]=fs[b*14+7+k];
    }
    if (tid==0){
        float smooth=0.f, shiftsum=0.f, ampsum=0.f;
        for (int b=0;b<8;b++){
            const float* l = fs + b*14;   // lo row
            float prev=0.f, nrm=0.f;
            for (int k=0;k<7;k++){ smooth += fabsf(l[k]-prev); prev=l[k]; nrm += l[k]*l[k]; }
            smooth += fabsf(prev);
            float denom = sqrtf(nrm) + 1e-8f;
            float sabs=0.f, s2=0.f;
            for (int k=0;k<7;k++){ float v=l[k]/denom; sabs+=fabsf(v); s2+=v*v; }
            shiftsum += sabs*sabs;
            ampsum += fabsf(s2-1.0f);
        }
        smooth *= (1.0f/64.0f);
        float shift = 3.0f*shiftsum/(8.0f*49.0f);
        float amp = ampsum*(1.0f/8.0f);
        *ortho_out = 0.01f*(shift+amp) + 0.1f*smooth;
    }
}

// -------- per-batch 7-tap filter conv (edge pad) + optional stat acc --------
__global__ __launch_bounds__(256) void filt_kernel(
    const float* __restrict__ ap, const float* __restrict__ lo,
    const float* __restrict__ hi, float* __restrict__ na,
    float* __restrict__ det, float* __restrict__ stat_out)
{
    int r = blockIdx.y, l0 = blockIdx.x*256, tid = threadIdx.x;
    int b = r>>6;
    __shared__ float s[262];
    __shared__ float fl[7], fh[7];
    __shared__ float sred[4];
    for (int idx=tid; idx<262; idx+=256){
        int l = l0+idx-3;
        l = min(max(l,0),LSEQ-1);
        s[idx]=ap[(size_t)r*LSEQ+l];
    }
    if (tid<7) fl[tid]=lo[b*7+tid];
    else if (tid<14) fh[tid-7]=hi[b*7+tid-7];
    __syncthreads();
    float a=0.f, d=0.f;
    #pragma unroll
    for (int k=0;k<7;k++){ float v=s[tid+k]; a+=v*fl[k]; d+=v*fh[k]; }
    na[(size_t)r*LSEQ+l0+tid]=a;
    det[(size_t)r*LSEQ+l0+tid]=d;
    if (stat_out){
        float sm=a;
        for (int o=32;o>0;o>>=1) sm += __shfl_down(sm,o,64);
        if ((tid&63)==0) sred[tid>>6]=sm;
        __syncthreads();
        if (tid==0) atomicAdd(&stat_out[r], sred[0]+sred[1]+sred[2]+sred[3]);
    }
}

// ---------------- time grid pass1: per-row stats (batched over levels) ------
__global__ __launch_bounds__(256) void tg_pass1(const float* __restrict__ CB,
                                                float* __restrict__ rowstats){
    __shared__ float sh[2048];
    __shared__ float red[28];
    int r = blockIdx.x, lvl = blockIdx.y, tid = threadIdx.x;
    const float* s = CB + (size_t)lvl*NTOT + (size_t)r*LSEQ;
    float* rso = rowstats + (size_t)(lvl*NROWS+r)*8;
    for (int i=tid;i<2048;i+=256) sh[i]=s[i];
    __syncthreads();
    float ssq=0.f;
    for (int i=tid;i<2048;i+=256){ float v=sh[i]; ssq+=v*v; }
    float mn=1e30f, mx=-1e30f, s0=0.f,s1=0.f,s2=0.f,s3=0.f;
    for (int j=tid;j<2047;j+=256){
        int k0 = (j-2>0)? j-2:0;
        int k1 = (j+2<2046)? j+2:2046;
        float acc=0.f;
        for (int k=k0;k<=k1;k++) acc += fabsf(sh[k+1]-sh[k]);
        float inten = acc*0.2f;
        mn=fminf(mn,inten); mx=fmaxf(mx,inten);
        if (j<511)  s0+=inten;
        if (j<1023) s1+=inten;
        if (j<1534) s2+=inten;
        if (j<2046) s3+=inten;
    }
    float vals[7]={mn,mx,s0,s1,s2,s3,ssq};
    for (int o=32;o>0;o>>=1){
        vals[0]=fminf(vals[0],__shfl_down(vals[0],o,64));
        vals[1]=fmaxf(vals[1],__shfl_down(vals[1],o,64));
        vals[2]+=__shfl_down(vals[2],o,64);
        vals[3]+=__shfl_down(vals[3],o,64);
        vals[4]+=__shfl_down(vals[4],o,64);
        vals[5]+=__shfl_down(vals[5],o,64);
        vals[6]+=__shfl_down(vals[6],o,64);
    }
    int lane=tid&63, w=tid>>6;
    if (lane==0) for (int q=0;q<7;q++) red[w*7+q]=vals[q];
    __syncthreads();
    if (tid==0){
        rso[0]=fminf(fminf(red[0],red[7]),fminf(red[14],red[21]));
        rso[1]=fmaxf(fmaxf(red[1],red[8]),fmaxf(red[15],red[22]));
        rso[2]=red[2]+red[9]+red[16]+red[23];
        rso[3]=red[3]+red[10]+red[17]+red[24];
        rso[4]=red[4]+red[11]+red[18]+red[25];
        rso[5]=red[5]+red[12]+red[19]+red[26];
        rso[6]=red[6]+red[13]+red[20]+red[27];
    }
}

// ---------------- time grid finalize + modulation (grid = 4 levels) ---------
__global__ __launch_bounds__(256) void tg_finalize(
    const float* __restrict__ rowstats,
    const float* __restrict__ wt, const float* __restrict__ bt,
    const float* __restrict__ wm, const float* __restrict__ bm,
    const float* __restrict__ emb,
    float* __restrict__ ts_out, float* __restrict__ modsc,
    float* __restrict__ modbi, float* __restrict__ ein,
    float* __restrict__ eout)
{
    int tid=threadIdx.x;
    const int lvl=blockIdx.x;
    const float* rs = rowstats + (size_t)lvl*NROWS*8;
    __shared__ float red[28];
    __shared__ float stv[9];
    __shared__ float temb[144];
    float mn=1e30f,mx=-1e30f,a0=0.f,a1=0.f,a2=0.f,a3=0.f,m3=-1e30f;
    for (int r=tid;r<512;r+=256){
        mn=fminf(mn,rs[r*8+0]); mx=fmaxf(mx,rs[r*8+1]);
        a0+=rs[r*8+2]; a1+=rs[r*8+3]; a2+=rs[r*8+4]; a3+=rs[r*8+5];
        m3=fmaxf(m3,rs[r*8+5]);
    }
    float vals[7]={mn,mx,a0,a1,a2,a3,m3};
    for (int o=32;o>0;o>>=1){
        vals[0]=fminf(vals[0],__shfl_down(vals[0],o,64));
        vals[1]=fmaxf(vals[1],__shfl_down(vals[1],o,64));
        vals[2]+=__shfl_down(vals[2],o,64);
        vals[3]+=__shfl_down(vals[3],o,64);
        vals[4]+=__shfl_down(vals[4],o,64);
        vals[5]+=__shfl_down(vals[5],o,64);
        vals[6]=fmaxf(vals[6],__shfl_down(vals[6],o,64));
    }
    int lane=tid&63, w=tid>>6;
    if (lane==0) for (int q=0;q<7;q++) red[w*7+q]=vals[q];
    if (tid<8){
        float e=0.f;
        for (int c=0;c<64;c++) e += rs[(tid*64+c)*8+6];
        ein[lvl*8+tid]=e*(1.0f/131072.0f);
        eout[lvl*8+tid]=0.f;
    }
    __syncthreads();
    if (tid==0){
        float mnv=fminf(fminf(red[0],red[7]),fminf(red[14],red[21]));
        float mxv=fmaxf(fmaxf(red[1],red[8]),fmaxf(red[15],red[22]));
        float s0=red[2]+red[9]+red[16]+red[23];
        float s1=red[3]+red[10]+red[17]+red[24];
        float s2=red[4]+red[11]+red[18]+red[25];
        float s3=red[5]+red[12]+red[19]+red[26];
        float m3v=fmaxf(fmaxf(red[6],red[13]),fmaxf(red[20],red[27]));
        const float idxs[5]={0.f,511.f,1023.f,1534.f,2046.f};
        float tsv[5];
        if (mxv-mnv < 1e-8f){
            for (int k=0;k<5;k++) tsv[k]=idxs[k]/2046.0f;
        } else {
            float a = 0.9f/(mxv-mnv+1e-30f);
            float bb = 0.1f - a*mnv;
            float gmax = a*m3v + bb*2046.0f;
            float sums[5]={0.f,s0,s1,s2,s3};
            tsv[0]=0.f;
            for (int k=1;k<5;k++)
                tsv[k]=(a*(sums[k]*(1.0f/512.0f)) + bb*idxs[k])/gmax;
        }
        for (int k=0;k<5;k++){ ts_out[lvl*8+k]=tsv[k]; stv[2*k]=tsv[k]; }
        for (int k=0;k<4;k++) stv[2*k+1]=tsv[k] + 0.5f*(tsv[k+1]-tsv[k]);
    }
    __syncthreads();
    if (tid<144){
        int m=tid>>4, i=tid&15;
        float z = wt[lvl*16+i]*stv[m] + bt[lvl*16+i];
        temb[tid]=siluf(z);
    }
    __syncthreads();
    for (int idx=tid; idx<1152; idx+=256){
        int m=idx>>7, c=idx&127;
        float g=bm[lvl*128+c];
        const float* W=wm+(size_t)(lvl*128+c)*16;
        const float* te=temb+m*16;
        for (int i=0;i<16;i++) g += W[i]*te[i];
        if (c<64) modsc[lvl*576+m*64+c]=1.0f+g+emb[(lvl*8+lvl)*64+c];
        else      modbi[lvl*576+m*64+(c-64)]=g;
    }
}

// ---------------- MFMA fused ode_f eval (64-pos tiles, 28.4 KB LDS) ---------
// grid (32, 8, 4): (64-pos tile, batch, level). block 256 = 4 waves.
// conv1: 3-term split (y hi+lo). conv2: 2-term (Whi+Wlo)*h_hi, h stored hi-only.
// k1..k3 and acc live in GLOBAL packed-bf16 pair buffers [lvl][b][ci/2][l].
__global__ __launch_bounds__(256) void ode_eval_all(
    const float* __restrict__ yinB, const unsigned* __restrict__ kprevB,
    unsigned* __restrict__ koutB, unsigned* __restrict__ accB,
    float* __restrict__ youtB,
    const short* __restrict__ WB, const float* __restrict__ c1bB,
    const float* __restrict__ c2bB,
    const float* __restrict__ modscB, const float* __restrict__ modbiB,
    const float* __restrict__ tsB, float* __restrict__ eoutB,
    int step, int eval, int do_energy)
{
    __shared__ unsigned yTh[68][36];   // row r <-> ye pos l0-2+r ; packed ci pairs
    __shared__ unsigned yTl[68][36];
    __shared__ unsigned hTh[66][36];   // row r <-> h pos l0-1+r (hi only)
    __shared__ float red[4];
    const int tid=threadIdx.x;
    const int lvl=blockIdx.z;
    const int b=blockIdx.y;
    const int l0=blockIdx.x*64;
    const size_t loff=(size_t)lvl*NTOT;
    const size_t loffP=(size_t)lvl*(NTOT/2);
    const float* yin = yinB + loff;
    const unsigned* kprev = kprevB + loffP;
    unsigned* kout = koutB + loffP;
    unsigned* acc = accB + loffP;
    float* yout = youtB + loff;
    const float dt = tsB[lvl*8+step+1]-tsB[lvl*8+step];
    const float alpha=(eval==0)?0.f:((eval==3)?dt:0.5f*dt);
    const int tslot=2*step+((eval==0)?0:((eval==3)?2:1));
    const int wv=tid>>6, lane=tid&63;
    const int n=lane&15, quad=lane>>4;
    const int m0=wv*16;

    // ---- stage ye (+alpha*kprev) into split-bf16 transposed tiles ----
    #pragma unroll
    for (int pass=0; pass<2; pass++){
        int r = pass*64 + lane;
        if (r < 68){
            int l = l0 - 2 + r;
            bool ok = (l>=0 && l<LSEQ);
            #pragma unroll
            for (int qq=0; qq<8; qq++){
                int q = wv*8 + qq;
                float v0=0.f, v1=0.f;
                if (ok){
                    size_t g0=(size_t)(b*64+2*q)*LSEQ+l;
                    v0=yin[g0]; v1=yin[g0+LSEQ];
                    if (eval!=0){
                        unsigned ku = kprev[((size_t)(b*32+q))*LSEQ + l];
                        v0 += alpha*bf2f(ku);
                        v1 += alpha*bf2f(ku>>16);
                    }
                }
                unsigned short h0=f2bf(v0), h1=f2bf(v1);
                yTh[r][q] = (unsigned)h0 | ((unsigned)h1<<16);
                yTl[r][q] = (unsigned)f2bf(v0-bf2f(h0)) | ((unsigned)f2bf(v1-bf2f(h1))<<16);
            }
        }
    }
    __syncthreads();

    // ---- conv1: h pos l0-1..l0+64 (5 n-tiles; tile 4 only n<2 stored) ----
    {
        const short* W1 = WB + (size_t)(lvl*2+0)*2*3*4096;
        short8 A[3][2][2];
        #pragma unroll
        for (int tap=0;tap<3;tap++)
            #pragma unroll
            for (int ks=0;ks<2;ks++)
                #pragma unroll
                for (int hl=0;hl<2;hl++)
                    A[tap][ks][hl] = *(const short8*)(W1 + (((size_t)hl*3+tap)*64 + (m0+n))*64 + ks*32 + quad*8);
        float bia[4];
        #pragma unroll
        for (int reg=0;reg<4;reg++) bia[reg]=c1bB[lvl*64 + m0 + quad*4 + reg];
        const int q0=(m0>>1)+quad*2;
        for (int nt=0; nt<5; nt++){
            float4v d = {bia[0],bia[1],bia[2],bia[3]};
            #pragma unroll
            for (int tap=0;tap<3;tap++){
                int rr = 16*nt + n + tap;
                rr = (rr>67)? 67 : rr;           // clamp (junk rows unused)
                const unsigned* ph=&yTh[rr][0];
                const unsigned* pl=&yTl[rr][0];
                #pragma unroll
                for (int ks=0;ks<2;ks++){
                    short8 bh = *(const short8*)(ph + ks*16 + quad*4);
                    short8 bl = *(const short8*)(pl + ks*16 + quad*4);
                    d = __builtin_amdgcn_mfma_f32_16x16x32_bf16(A[tap][ks][0], bh, d, 0,0,0);
                    d = __builtin_amdgcn_mfma_f32_16x16x32_bf16(A[tap][ks][0], bl, d, 0,0,0);
                    d = __builtin_amdgcn_mfma_f32_16x16x32_bf16(A[tap][ks][1], bh, d, 0,0,0);
                }
            }
            if (nt<4 || n<2){
                int rh = 16*nt + n;
                int hpos = l0 - 1 + rh;
                bool okh = (hpos>=0 && hpos<LSEQ);
                float h0 = okh? geluf(d[0]) : 0.f;
                float h1 = okh? geluf(d[1]) : 0.f;
                float h2 = okh? geluf(d[2]) : 0.f;
                float h3 = okh? geluf(d[3]) : 0.f;
                hTh[rh][q0]   = (unsigned)f2bf(h0) | ((unsigned)f2bf(h1)<<16);
                hTh[rh][q0+1] = (unsigned)f2bf(h2) | ((unsigned)f2bf(h3)<<16);
            }
        }
    }
    __syncthreads();

    // ---- conv2 (4 n-tiles, output pos l0..l0+63) + packed epilogue ----
    float esum=0.f;
    {
        const short* W2 = WB + (size_t)(lvl*2+1)*2*3*4096;
        short8 A[3][2][2];
        #pragma unroll
        for (int tap=0;tap<3;tap++)
            #pragma unroll
            for (int ks=0;ks<2;ks++)
                #pragma unroll
                for (int hl=0;hl<2;hl++)
                    A[tap][ks][hl] = *(const short8*)(W2 + (((size_t)hl*3+tap)*64 + (m0+n))*64 + ks*32 + quad*8);
        float bib[4], sc[4], bi2[4];
        #pragma unroll
        for (int reg=0;reg<4;reg++){
            int co = m0 + quad*4 + reg;
            bib[reg]=c2bB[lvl*64+co];
            sc[reg]=modscB[lvl*576+tslot*64+co];
            bi2[reg]=modbiB[lvl*576+tslot*64+co];
        }
        const float dt6 = dt/6.0f;
        const int qy0=(m0+quad*4)>>1;
        for (int nt=0; nt<4; nt++){
            float4v d = {bib[0],bib[1],bib[2],bib[3]};
            #pragma unroll
            for (int tap=0;tap<3;tap++){
                const int rr = 16*nt + n + tap;
                const unsigned* ph=&hTh[rr][0];
                #pragma unroll
                for (int ks=0;ks<2;ks++){
                    short8 bh = *(const short8*)(ph + ks*16 + quad*4);
                    d = __builtin_amdgcn_mfma_f32_16x16x32_bf16(A[tap][ks][0], bh, d, 0,0,0);
                    d = __builtin_amdgcn_mfma_f32_16x16x32_bf16(A[tap][ks][1], bh, d, 0,0,0);
                }
            }
            int p = l0 + 16*nt + n;
            int ry = 16*nt + n + 2;
            unsigned uh0=yTh[ry][qy0],   ul0=yTl[ry][qy0];
            unsigned uh1=yTh[ry][qy0+1], ul1=yTl[ry][qy0+1];
            float yev[4];
            yev[0]=bf2f(uh0)+bf2f(ul0);
            yev[1]=bf2f(uh0>>16)+bf2f(ul0>>16);
            yev[2]=bf2f(uh1)+bf2f(ul1);
            yev[3]=bf2f(uh1>>16)+bf2f(ul1>>16);
            float kv[4];
            #pragma unroll
            for (int reg=0;reg<4;reg++){
                float m = d[reg]*sc[reg] + bi2[reg];
                kv[reg] = siluf(m) - 0.1f*yev[reg];
            }
            size_t ia = ((size_t)(b*32+qy0))*LSEQ + p;
            size_t ib = ia + LSEQ;
            if (eval==0){
                unsigned ka=(unsigned)f2bf(kv[0])|((unsigned)f2bf(kv[1])<<16);
                unsigned kb=(unsigned)f2bf(kv[2])|((unsigned)f2bf(kv[3])<<16);
                kout[ia]=ka; kout[ib]=kb;
                acc[ia]=ka;  acc[ib]=kb;
            } else if (eval<3){
                unsigned ka=(unsigned)f2bf(kv[0])|((unsigned)f2bf(kv[1])<<16);
                unsigned kb=(unsigned)f2bf(kv[2])|((unsigned)f2bf(kv[3])<<16);
                kout[ia]=ka; kout[ib]=kb;
                unsigned ua=acc[ia], ub=acc[ib];
                float a0=bf2f(ua)+2.f*kv[0],     a1=bf2f(ua>>16)+2.f*kv[1];
                float a2=bf2f(ub)+2.f*kv[2],     a3=bf2f(ub>>16)+2.f*kv[3];
                acc[ia]=(unsigned)f2bf(a0)|((unsigned)f2bf(a1)<<16);
                acc[ib]=(unsigned)f2bf(a2)|((unsigned)f2bf(a3)<<16);
            } else {
                unsigned ua=acc[ia], ub=acc[ib];
                float av[4]={bf2f(ua),bf2f(ua>>16),bf2f(ub),bf2f(ub>>16)};
                size_t gbase=(size_t)(b*64 + m0 + quad*4)*LSEQ + p;
                #pragma unroll
                for (int reg=0;reg<4;reg++){
                    size_t gi = gbase + (size_t)reg*LSEQ;
                    float yn = yin[gi] + dt6*(av[reg]+kv[reg]);
                    yout[gi]=yn;
                    esum += yn*yn;
                }
            }
        }
    }
    if (do_energy){
        for (int o=32;o>0;o>>=1) esum+=__shfl_down(esum,o,64);
        if ((tid&63)==0) red[tid>>6]=esum;
        __syncthreads();
        if (tid==0) atomicAdd(&eoutB[lvl*8+b], red[0]+red[1]+red[2]+red[3]);
    }
}

// -------- fused reconstruction: scale + [attn] + gate + residual ------------
// grid (32, NB). cur scaled by s(lvl_cur) on load (if lvl_cur>=0);
// detail read from det_in scaled by s(lvl_det); final detail written to det_out.
__global__ __launch_bounds__(256) void recon_kernel(
    const float* __restrict__ cur, const float* __restrict__ det_in,
    float* __restrict__ det_out,
    const float* __restrict__ a1w, const float* __restrict__ a1b,
    const float* __restrict__ a2w, const float* __restrict__ a2b,
    const float* __restrict__ gwt, const float* __restrict__ gb,
    float* __restrict__ curout,
    const float* __restrict__ ein, const float* __restrict__ eout,
    int lvl_cur, int lvl_det, int has_attn)
{
    __shared__ float yc[64][66];
    __shared__ float dtile[64][65];
    __shared__ float hid[16][64];
    const int tid=threadIdx.x, b=blockIdx.y, l0=blockIdx.x*64;
    float scur=1.f, sdet;
    if (lvl_cur>=0){
        float eo=eout[lvl_cur*8+b]*(1.0f/131072.0f);
        scur=sqrtf(ein[lvl_cur*8+b]/(eo+1e-8f));
    }
    {
        float eo=eout[lvl_det*8+b]*(1.0f/131072.0f);
        sdet=sqrtf(ein[lvl_det*8+b]/(eo+1e-8f));
    }
    for (int idx=tid; idx<64*66; idx+=256){
        int ci=idx/66, u=idx-ci*66;
        int l=l0+u-1;
        yc[ci][u]=(l>=0 && l<LSEQ)? scur*cur[(size_t)(b*64+ci)*LSEQ+l] : 0.f;
    }
    for (int idx=tid; idx<4096; idx+=256){
        int ci=idx>>6, p=idx&63;
        dtile[ci][p]=sdet*det_in[(size_t)(b*64+ci)*LSEQ+l0+p];
    }
    __syncthreads();
    if (has_attn){
        for (int idx=tid; idx<1024; idx+=256){
            int h=idx>>6, p=idx&63;
            float acc=a1b[h];
            const float* W=a1w+h*64;
            for (int ci=0;ci<64;ci++) acc += W[ci]*yc[ci][p+1];
            hid[h][p]=geluf(acc);
        }
        __syncthreads();
        for (int idx=tid; idx<4096; idx+=256){
            int co=idx>>6, p=idx&63;
            float acc=a2b[co];
            const float* W=a2w+co*16;
            #pragma unroll
            for (int h=0;h<16;h++) acc += W[h]*hid[h][p];
            float a=sigf(acc);
            float dnew = dtile[co][p]*(1.0f+a);
            dtile[co][p]=dnew;
            det_out[(size_t)(b*64+co)*LSEQ+l0+p]=dnew;
        }
        __syncthreads();
    } else {
        for (int idx=tid; idx<4096; idx+=256){
            int ci=idx>>6, p=idx&63;
            det_out[(size_t)(b*64+ci)*LSEQ+l0+p]=dtile[ci][p];
        }
    }
    const int co=tid&63, g=tid>>6;
    const int p0=g*16;
    float a[16];
    float bb=gb[co];
    #pragma unroll
    for (int i=0;i<16;i++) a[i]=bb;
    for (int ci=0;ci<64;ci++){
        float w0=gwt[(ci*3+0)*64+co];
        float w1_=gwt[(ci*3+1)*64+co];
        float w2_=gwt[(ci*3+2)*64+co];
        float x[18];
        #pragma unroll
        for (int j=0;j<18;j++) x[j]=yc[ci][p0+j];
        #pragma unroll
        for (int i=0;i<16;i++) a[i] += w0*x[i]+w1_*x[i+1]+w2_*x[i+2];
    }
    float r[16];
    #pragma unroll
    for (int i=0;i<16;i++){
        float gt=sigf(a[i]);
        r[i]=yc[co][p0+i+1]+gt*dtile[co][p0+i];
    }
    __syncthreads();
    #pragma unroll
    for (int i=0;i<16;i++) dtile[co][p0+i]=r[i];
    __syncthreads();
    for (int idx=tid; idx<4096; idx+=256){
        int ci=idx>>6, p=idx&63;
        curout[(size_t)(b*64+ci)*LSEQ+l0+p]=dtile[ci][p];
    }
}

extern "C" void kernel_launch(void* const* d_in, const int* in_sizes, int n_in,
                              void* d_out, int out_size, void* d_ws, size_t ws_size,
                              hipStream_t stream)
{
    (void)in_sizes; (void)n_in; (void)out_size; (void)ws_size;
    const float* x       =(const float*)d_in[0];
    const float* dy_w1   =(const float*)d_in[1];
    const float* dy_b1   =(const float*)d_in[2];
    const float* dy_wg1  =(const float*)d_in[3];
    const float* dy_bg1  =(const float*)d_in[4];
    const float* dy_wg2  =(const float*)d_in[5];
    const float* dy_bg2  =(const float*)d_in[6];
    const float* ode_c1w =(const float*)d_in[7];
    const float* ode_c1b =(const float*)d_in[8];
    const float* ode_c2w =(const float*)d_in[9];
    const float* ode_c2b =(const float*)d_in[10];
    const float* ode_wt  =(const float*)d_in[11];
    const float* ode_bt  =(const float*)d_in[12];
    const float* ode_wm  =(const float*)d_in[13];
    const float* ode_bm  =(const float*)d_in[14];
    const float* ode_emb =(const float*)d_in[15];
    const float* gate_w  =(const float*)d_in[16];
    const float* gate_b  =(const float*)d_in[17];
    const float* attn1_w =(const float*)d_in[18];
    const float* attn1_b =(const float*)d_in[19];
    const float* attn2_w =(const float*)d_in[20];
    const float* attn2_b =(const float*)d_in[21];
    float* out=(float*)d_out;
    float* ws=(float*)d_ws;
    const size_t N=NTOT;
    // workspace layout (floats)
    float* CB = ws;                      // coeff[4]: A0, D1, D2, D3 (4N)
    float* PB = ws+4*N;                  // y ping (4 levels) — also decomp temps
    float* QB = ws+8*N;                  // y pong (4 levels)
    unsigned* K0P=(unsigned*)(ws+12*N);  // packed-bf16 k ping (2N floats)
    unsigned* K1P=(unsigned*)(ws+14*N);  // packed-bf16 k pong
    unsigned* ACP=(unsigned*)(ws+16*N);  // packed-bf16 acc
    float* SM = ws+20*N;
    float* stat_ws =SM;          // 512
    float* lo_ws   =SM+512;      // 64
    float* hi_ws   =SM+576;      // 64
    float* rowstats=SM+1024;     // 4*512*8 = 16384
    float* ts_ws   =SM+17408;    // 4*8
    float* modsc   =SM+17536;    // 4*576
    float* modbi   =SM+19840;    // 4*576
    float* ein     =SM+22144;    // 32
    float* eoutb   =SM+22176;    // 32
    short* WB      =(short*)(SM+24576);  // 393216 bf16 = 196608 floats
    float* WTG     =SM+24576+196608;     // 3*12288 (gate weights, transposed)

    dim3 blk(256);

    wprep_kernel<<<768,blk,0,stream>>>(ode_c1w, ode_c2w, WB);
    for (int i=0;i<3;i++)
        wtrans_kernel<<<48,blk,0,stream>>>(gate_w+(size_t)i*12288, WTG+(size_t)i*12288);

    // ---- wavelet decomposition (3 levels, sequential; stat fused in filt) --
    stat_kernel<<<NROWS,blk,0,stream>>>(x, stat_ws);
    const float* cura=x;
    float* outsA[3]={PB, PB+N, CB};      // T0, T1, A0-final
    float* outsD[3]={CB+N, CB+2*N, CB+3*N};
    for (int lv=0; lv<3; lv++){
        dywan_kernel<<<1,blk,0,stream>>>(stat_ws, dy_w1,dy_b1,dy_wg1,dy_bg1,dy_wg2,dy_bg2,
                                         lo_ws, hi_ws, out+4*N);
        float* statn = (lv<2)? stat_ws : nullptr;
        filt_kernel<<<dim3(8,NROWS),blk,0,stream>>>(cura, lo_ws, hi_ws,
                                                    outsA[lv], outsD[lv], statn);
        cura=outsA[lv];
    }

    // ---- adaptive grids + modulation for all 4 levels ----
    tg_pass1<<<dim3(NROWS,4),blk,0,stream>>>(CB, rowstats);
    tg_finalize<<<4,blk,0,stream>>>(rowstats, ode_wt, ode_bt, ode_wm, ode_bm,
                                    ode_emb, ts_ws, modsc, modbi, ein, eoutb);

    // ---- RK4: 16 evals, each batched over 4 levels ----
    const float* yins[4]={CB, PB, QB, PB};
    float*       youts[4]={PB, QB, PB, QB};
    for (int step=0;step<4;step++){
        for (int ev=0;ev<4;ev++){
            const unsigned* kp=(ev==2)? K1P : K0P;
            unsigned* ko=(ev==1)? K1P : K0P;
            int doe=(step==3 && ev==3)?1:0;
            ode_eval_all<<<dim3(32,NB,4),blk,0,stream>>>(
                yins[step],kp,ko,ACP,youts[step],
                WB,ode_c1b,ode_c2b,modsc,modbi,ts_ws,eoutb,step,ev,doe);
        }
    }

    // ---- reconstruction (fused scale+attn+gate); evolved lives in QB ----
    // i=2: cur=s0*QB0, detail=s3*QB3 -> out3; current -> PB
    recon_kernel<<<dim3(32,NB),blk,0,stream>>>(QB+0*N, QB+3*N, out+3*N,
        attn1_w, attn1_b, attn2_w, attn2_b,
        WTG+2*12288, gate_b+128, PB, ein, eoutb, 0, 3, 0);
    // i=1: cur=PB, detail=s2*QB2 + attn(set1) -> out2; current -> QB(slot0)
    recon_kernel<<<dim3(32,NB),blk,0,stream>>>(PB, QB+2*N, out+2*N,
        attn1_w+1024, attn1_b+16, attn2_w+1024, attn2_b+64,
        WTG+1*12288, gate_b+64, QB, ein, eoutb, -1, 2, 1);
    // i=0: cur=QB(slot0), detail=s1*QB1 + attn(set0) -> out1; current -> out0
    recon_kernel<<<dim3(32,NB),blk,0,stream>>>(QB, QB+1*N, out+1*N,
        attn1_w, attn1_b, attn2_w, attn2_b,
        WTG, gate_b, out+0*N, ein, eoutb, -1, 1, 1);
}

// Round 15
// 745.849 us; speedup vs baseline: 1.2466x; 1.0072x over previous
//
#include <hip/hip_runtime.h>
#include <math.h>

#define LSEQ 2048
#define NB 8
#define NCH 64
#define NTOT (NB*NCH*LSEQ)   // 1048576
#define NROWS (NB*NCH)       // 512

typedef __attribute__((ext_vector_type(8))) short short8;
typedef __attribute__((ext_vector_type(4))) float float4v;

__device__ __forceinline__ float geluf(float x){
    return 0.5f*x*(1.0f+erff(x*0.70710678118654752f));
}
__device__ __forceinline__ float siluf(float x){
    return x/(1.0f+expf(-x));
}
__device__ __forceinline__ float sigf(float x){
    return 1.0f/(1.0f+expf(-x));
}
__device__ __forceinline__ unsigned short f2bf(float f){
    unsigned u=__float_as_uint(f);
    u += 0x7fffu + ((u>>16)&1u);
    return (unsigned short)(u>>16);
}
__device__ __forceinline__ float bf2f(unsigned h){
    return __uint_as_float((h&0xffffu)<<16);
}

// ---------------- weight transpose: w[64][64][3] -> wt[192][64] (gate) ------
__global__ __launch_bounds__(256) void wtrans_kernel(const float* __restrict__ w,
                                                     float* __restrict__ wt){
    int idx = blockIdx.x*256 + threadIdx.x;   // 12288 total
    int j = idx >> 6, co = idx & 63;
    wt[idx] = w[co*192 + j];
}

// ---- ode weight split-prep: WB[lvl][st][hl][tap][co][ci] bf16 --------------
__global__ __launch_bounds__(256) void wprep_kernel(const float* __restrict__ c1w,
                                                    const float* __restrict__ c2w,
                                                    short* __restrict__ WB){
    int idx = blockIdx.x*256 + threadIdx.x;   // 4*2*3*64*64 = 196608
    if (idx >= 196608) return;
    int ci  = idx & 63;
    int co  = (idx>>6) & 63;
    int tap = (idx>>12) % 3;
    int st  = (idx/(3<<12)) & 1;
    int lvl = idx/(6<<12);
    const float* src = (st==0? c1w : c2w);
    float w = src[(size_t)lvl*12288 + co*192 + ci*3 + tap];
    unsigned short hi = f2bf(w);
    float lo = w - bf2f(hi);
    size_t base = ((((size_t)(lvl*2+st)*2+0)*3+tap)*64+co)*64+ci;
    size_t basl = ((((size_t)(lvl*2+st)*2+1)*3+tap)*64+co)*64+ci;
    WB[base] = (short)hi;
    WB[basl] = (short)f2bf(lo);
}

// ---------------- stat = ROW SUMS over L (dywan normalizes) -----------------
__global__ __launch_bounds__(256) void stat_kernel(const float* __restrict__ in,
                                                   float* __restrict__ stat){
    int r = blockIdx.x, tid = threadIdx.x;
    const float* p = in + (size_t)r*LSEQ;
    float acc = 0.f;
    for (int i=tid;i<LSEQ;i+=256) acc += p[i];
    for (int o=32;o>0;o>>=1) acc += __shfl_down(acc,o,64);
    __shared__ float red[4];
    if ((tid&63)==0) red[tid>>6]=acc;
    __syncthreads();
    if (tid==0) stat[r] = red[0]+red[1]+red[2]+red[3];
}

// ---------------- dywan MLP + filters + ortho (stat = raw sums) -------------
__global__ __launch_bounds__(256) void dywan_kernel(
    float* __restrict__ stat,
    const float* __restrict__ w1, const float* __restrict__ b1,
    const float* __restrict__ wg1, const float* __restrict__ bg1,
    const float* __restrict__ wg2, const float* __restrict__ bg2,
    float* __restrict__ lo_out, float* __restrict__ hi_out,
    float* __restrict__ ortho_out)
{
    __shared__ float st[512];
    __shared__ float h1s[512];
    __shared__ float h2s[1024];
    __shared__ float fs[112];
    int tid = threadIdx.x;
    for (int i=tid;i<512;i+=256) st[i]=stat[i]*(1.0f/LSEQ);
    __syncthreads();
    // reset stat accumulator for the next level's filt atomics
    for (int i=tid;i<512;i+=256) stat[i]=0.f;
    for (int idx=tid; idx<512; idx+=256){
        int b=idx>>6, j=idx&63;
        float acc=b1[j];
        const float* W=w1+j*64;
        for (int i=0;i<64;i++) acc += st[b*64+i]*W[i];
        h1s[idx]=geluf(acc);
    }
    __syncthreads();
    for (int idx=tid; idx<1024; idx+=256){
        int b=idx>>7, j=idx&127;
        float acc=bg1[j];
        const float* W=wg1+j*64;
        for (int i=0;i<64;i++) acc += h1s[b*64+i]*W[i];
        h2s[idx]=geluf(acc);
    }
    __syncthreads();
    if (tid<112){
        int b=tid/14, j=tid-b*14;
        float acc=bg2[j];
        const float* W=wg2+j*128;
        for (int i=0;i<128;i++) acc += h2s[b*128+i]*W[i];
        fs[tid]=acc;
    }
    __syncthreads();
    if (tid<56){
        int b=tid/7, k=tid-b*7;
        lo_out[tid]=fs[b*14+k];
        hi_out[tid]=fs[b*14+7+k];
    }
    if (tid==0){
        float smooth=0.f, shiftsum=0.f, ampsum=0.f;
        for (int b=0;b<8;b++){
            const float* l = fs + b*14;   // lo row
            float prev=0.f, nrm=0.f;
            for (int k=0;k<7;k++){ smooth += fabsf(l[k]-prev); prev=l[k]; nrm += l[k]*l[k]; }
            smooth += fabsf(prev);
            float denom = sqrtf(nrm) + 1e-8f;
            float sabs=0.f, s2=0.f;
            for (int k=0;k<7;k++){ float v=l[k]/denom; sabs+=fabsf(v); s2+=v*v; }
            shiftsum += sabs*sabs;
            ampsum += fabsf(s2-1.0f);
        }
        smooth *= (1.0f/64.0f);
        float shift = 3.0f*shiftsum/(8.0f*49.0f);
        float amp = ampsum*(1.0f/8.0f);
        *ortho_out = 0.01f*(shift+amp) + 0.1f*smooth;
    }
}

// -------- per-batch 7-tap filter conv (edge pad) + optional stat acc --------
__global__ __launch_bounds__(256) void filt_kernel(
    const float* __restrict__ ap, const float* __restrict__ lo,
    const float* __restrict__ hi, float* __restrict__ na,
    float* __restrict__ det, float* __restrict__ stat_out)
{
    int r = blockIdx.y, l0 = blockIdx.x*256, tid = threadIdx.x;
    int b = r>>6;
    __shared__ float s[262];
    __shared__ float fl[7], fh[7];
    __shared__ float sred[4];
    for (int idx=tid; idx<262; idx+=256){
        int l = l0+idx-3;
        l = min(max(l,0),LSEQ-1);
        s[idx]=ap[(size_t)r*LSEQ+l];
    }
    if (tid<7) fl[tid]=lo[b*7+tid];
    else if (tid<14) fh[tid-7]=hi[b*7+tid-7];
    __syncthreads();
    float a=0.f, d=0.f;
    #pragma unroll
    for (int k=0;k<7;k++){ float v=s[tid+k]; a+=v*fl[k]; d+=v*fh[k]; }
    na[(size_t)r*LSEQ+l0+tid]=a;
    det[(size_t)r*LSEQ+l0+tid]=d;
    if (stat_out){
        float sm=a;
        for (int o=32;o>0;o>>=1) sm += __shfl_down(sm,o,64);
        if ((tid&63)==0) sred[tid>>6]=sm;
        __syncthreads();
        if (tid==0) atomicAdd(&stat_out[r], sred[0]+sred[1]+sred[2]+sred[3]);
    }
}

// ---------------- time grid pass1: per-row stats (batched over levels) ------
__global__ __launch_bounds__(256) void tg_pass1(const float* __restrict__ CB,
                                                float* __restrict__ rowstats){
    __shared__ float sh[2048];
    __shared__ float red[28];
    int r = blockIdx.x, lvl = blockIdx.y, tid = threadIdx.x;
    const float* s = CB + (size_t)lvl*NTOT + (size_t)r*LSEQ;
    float* rso = rowstats + (size_t)(lvl*NROWS+r)*8;
    for (int i=tid;i<2048;i+=256) sh[i]=s[i];
    __syncthreads();
    float ssq=0.f;
    for (int i=tid;i<2048;i+=256){ float v=sh[i]; ssq+=v*v; }
    float mn=1e30f, mx=-1e30f, s0=0.f,s1=0.f,s2=0.f,s3=0.f;
    for (int j=tid;j<2047;j+=256){
        int k0 = (j-2>0)? j-2:0;
        int k1 = (j+2<2046)? j+2:2046;
        float acc=0.f;
        for (int k=k0;k<=k1;k++) acc += fabsf(sh[k+1]-sh[k]);
        float inten = acc*0.2f;
        mn=fminf(mn,inten); mx=fmaxf(mx,inten);
        if (j<511)  s0+=inten;
        if (j<1023) s1+=inten;
        if (j<1534) s2+=inten;
        if (j<2046) s3+=inten;
    }
    float vals[7]={mn,mx,s0,s1,s2,s3,ssq};
    for (int o=32;o>0;o>>=1){
        vals[0]=fminf(vals[0],__shfl_down(vals[0],o,64));
        vals[1]=fmaxf(vals[1],__shfl_down(vals[1],o,64));
        vals[2]+=__shfl_down(vals[2],o,64);
        vals[3]+=__shfl_down(vals[3],o,64);
        vals[4]+=__shfl_down(vals[4],o,64);
        vals[5]+=__shfl_down(vals[5],o,64);
        vals[6]+=__shfl_down(vals[6],o,64);
    }
    int lane=tid&63, w=tid>>6;
    if (lane==0) for (int q=0;q<7;q++) red[w*7+q]=vals[q];
    __syncthreads();
    if (tid==0){
        rso[0]=fminf(fminf(red[0],red[7]),fminf(red[14],red[21]));
        rso[1]=fmaxf(fmaxf(red[1],red[8]),fmaxf(red[15],red[22]));
        rso[2]=red[2]+red[9]+red[16]+red[23];
        rso[3]=red[3]+red[10]+red[17]+red[24];
        rso[4]=red[4]+red[11]+red[18]+red[25];
        rso[5]=red[5]+red[12]+red[19]+red[26];
        rso[6]=red[6]+red[13]+red[20]+red[27];
    }
}

// ---------------- time grid finalize + modulation (grid = 4 levels) ---------
__global__ __launch_bounds__(256) void tg_finalize(
    const float* __restrict__ rowstats,
    const float* __restrict__ wt, const float* __restrict__ bt,
    const float* __restrict__ wm, const float* __restrict__ bm,
    const float* __restrict__ emb,
    float* __restrict__ ts_out, float* __restrict__ modsc,
    float* __restrict__ modbi, float* __restrict__ ein,
    float* __restrict__ eout)
{
    int tid=threadIdx.x;
    const int lvl=blockIdx.x;
    const float* rs = rowstats + (size_t)lvl*NROWS*8;
    __shared__ float red[28];
    __shared__ float stv[9];
    __shared__ float temb[144];
    float mn=1e30f,mx=-1e30f,a0=0.f,a1=0.f,a2=0.f,a3=0.f,m3=-1e30f;
    for (int r=tid;r<512;r+=256){
        mn=fminf(mn,rs[r*8+0]); mx=fmaxf(mx,rs[r*8+1]);
        a0+=rs[r*8+2]; a1+=rs[r*8+3]; a2+=rs[r*8+4]; a3+=rs[r*8+5];
        m3=fmaxf(m3,rs[r*8+5]);
    }
    float vals[7]={mn,mx,a0,a1,a2,a3,m3};
    for (int o=32;o>0;o>>=1){
        vals[0]=fminf(vals[0],__shfl_down(vals[0],o,64));
        vals[1]=fmaxf(vals[1],__shfl_down(vals[1],o,64));
        vals[2]+=__shfl_down(vals[2],o,64);
        vals[3]+=__shfl_down(vals[3],o,64);
        vals[4]+=__shfl_down(vals[4],o,64);
        vals[5]+=__shfl_down(vals[5],o,64);
        vals[6]=fmaxf(vals[6],__shfl_down(vals[6],o,64));
    }
    int lane=tid&63, w=tid>>6;
    if (lane==0) for (int q=0;q<7;q++) red[w*7+q]=vals[q];
    if (tid<8){
        float e=0.f;
        for (int c=0;c<64;c++) e += rs[(tid*64+c)*8+6];
        ein[lvl*8+tid]=e*(1.0f/131072.0f);
        eout[lvl*8+tid]=0.f;
    }
    __syncthreads();
    if (tid==0){
        float mnv=fminf(fminf(red[0],red[7]),fminf(red[14],red[21]));
        float mxv=fmaxf(fmaxf(red[1],red[8]),fmaxf(red[15],red[22]));
        float s0=red[2]+red[9]+red[16]+red[23];
        float s1=red[3]+red[10]+red[17]+red[24];
        float s2=red[4]+red[11]+red[18]+red[25];
        float s3=red[5]+red[12]+red[19]+red[26];
        float m3v=fmaxf(fmaxf(red[6],red[13]),fmaxf(red[20],red[27]));
        const float idxs[5]={0.f,511.f,1023.f,1534.f,2046.f};
        float tsv[5];
        if (mxv-mnv < 1e-8f){
            for (int k=0;k<5;k++) tsv[k]=idxs[k]/2046.0f;
        } else {
            float a = 0.9f/(mxv-mnv+1e-30f);
            float bb = 0.1f - a*mnv;
            float gmax = a*m3v + bb*2046.0f;
            float sums[5]={0.f,s0,s1,s2,s3};
            tsv[0]=0.f;
            for (int k=1;k<5;k++)
                tsv[k]=(a*(sums[k]*(1.0f/512.0f)) + bb*idxs[k])/gmax;
        }
        for (int k=0;k<5;k++){ ts_out[lvl*8+k]=tsv[k]; stv[2*k]=tsv[k]; }
        for (int k=0;k<4;k++) stv[2*k+1]=tsv[k] + 0.5f*(tsv[k+1]-tsv[k]);
    }
    __syncthreads();
    if (tid<144){
        int m=tid>>4, i=tid&15;
        float z = wt[lvl*16+i]*stv[m] + bt[lvl*16+i];
        temb[tid]=siluf(z);
    }
    __syncthreads();
    for (int idx=tid; idx<1152; idx+=256){
        int m=idx>>7, c=idx&127;
        float g=bm[lvl*128+c];
        const float* W=wm+(size_t)(lvl*128+c)*16;
        const float* te=temb+m*16;
        for (int i=0;i<16;i++) g += W[i]*te[i];
        if (c<64) modsc[lvl*576+m*64+c]=1.0f+g+emb[(lvl*8+lvl)*64+c];
        else      modbi[lvl*576+m*64+(c-64)]=g;
    }
}

// ---------------- MFMA fused ode_f eval (64-pos tiles, 28.4 KB LDS) ---------
// grid (32, 8, 4): (64-pos tile, batch, level). block 256 = 4 waves.
// conv1: 3-term split (y hi+lo). conv2: 2-term (Whi+Wlo)*h_hi, h stored hi-only.
// k1..k3 in packed-bf16 pair buffers; acc read comes from accrdB (== k1 buffer
// after eval0, saving eval0's acc stores); acc written to accB for eval1/2.
__global__ __launch_bounds__(256) void ode_eval_all(
    const float* __restrict__ yinB, const unsigned* __restrict__ kprevB,
    unsigned* __restrict__ koutB, const unsigned* __restrict__ accrdB,
    unsigned* __restrict__ accB,
    float* __restrict__ youtB,
    const short* __restrict__ WB, const float* __restrict__ c1bB,
    const float* __restrict__ c2bB,
    const float* __restrict__ modscB, const float* __restrict__ modbiB,
    const float* __restrict__ tsB, float* __restrict__ eoutB,
    int step, int eval, int do_energy)
{
    __shared__ unsigned yTh[68][36];   // row r <-> ye pos l0-2+r ; packed ci pairs
    __shared__ unsigned yTl[68][36];
    __shared__ unsigned hTh[66][36];   // row r <-> h pos l0-1+r (hi only)
    __shared__ float red[4];
    const int tid=threadIdx.x;
    const int lvl=blockIdx.z;
    const int b=blockIdx.y;
    const int l0=blockIdx.x*64;
    const size_t loff=(size_t)lvl*NTOT;
    const size_t loffP=(size_t)lvl*(NTOT/2);
    const float* yin = yinB + loff;
    const unsigned* kprev = kprevB + loffP;
    unsigned* kout = koutB + loffP;
    const unsigned* accrd = accrdB + loffP;
    unsigned* acc = accB + loffP;
    float* yout = youtB + loff;
    const float dt = tsB[lvl*8+step+1]-tsB[lvl*8+step];
    const float alpha=(eval==0)?0.f:((eval==3)?dt:0.5f*dt);
    const int tslot=2*step+((eval==0)?0:((eval==3)?2:1));
    const int wv=tid>>6, lane=tid&63;
    const int n=lane&15, quad=lane>>4;
    const int m0=wv*16;

    // ---- stage ye (+alpha*kprev) into split-bf16 transposed tiles ----
    #pragma unroll
    for (int pass=0; pass<2; pass++){
        int r = pass*64 + lane;
        if (r < 68){
            int l = l0 - 2 + r;
            bool ok = (l>=0 && l<LSEQ);
            #pragma unroll
            for (int qq=0; qq<8; qq++){
                int q = wv*8 + qq;
                float v0=0.f, v1=0.f;
                if (ok){
                    size_t g0=(size_t)(b*64+2*q)*LSEQ+l;
                    v0=yin[g0]; v1=yin[g0+LSEQ];
                    if (eval!=0){
                        unsigned ku = kprev[((size_t)(b*32+q))*LSEQ + l];
                        v0 += alpha*bf2f(ku);
                        v1 += alpha*bf2f(ku>>16);
                    }
                }
                unsigned short h0=f2bf(v0), h1=f2bf(v1);
                yTh[r][q] = (unsigned)h0 | ((unsigned)h1<<16);
                yTl[r][q] = (unsigned)f2bf(v0-bf2f(h0)) | ((unsigned)f2bf(v1-bf2f(h1))<<16);
            }
        }
    }
    __syncthreads();

    // ---- conv1: h pos l0-1..l0+64 (5 n-tiles; tile 4 only n<2 stored) ----
    {
        const short* W1 = WB + (size_t)(lvl*2+0)*2*3*4096;
        short8 A[3][2][2];
        #pragma unroll
        for (int tap=0;tap<3;tap++)
            #pragma unroll
            for (int ks=0;ks<2;ks++)
                #pragma unroll
                for (int hl=0;hl<2;hl++)
                    A[tap][ks][hl] = *(const short8*)(W1 + (((size_t)hl*3+tap)*64 + (m0+n))*64 + ks*32 + quad*8);
        float bia[4];
        #pragma unroll
        for (int reg=0;reg<4;reg++) bia[reg]=c1bB[lvl*64 + m0 + quad*4 + reg];
        const int q0=(m0>>1)+quad*2;
        #pragma unroll
        for (int nt=0; nt<5; nt++){
            float4v d = {bia[0],bia[1],bia[2],bia[3]};
            #pragma unroll
            for (int tap=0;tap<3;tap++){
                int rr = 16*nt + n + tap;
                rr = (rr>67)? 67 : rr;           // clamp (junk rows unused)
                const unsigned* ph=&yTh[rr][0];
                const unsigned* pl=&yTl[rr][0];
                #pragma unroll
                for (int ks=0;ks<2;ks++){
                    short8 bh = *(const short8*)(ph + ks*16 + quad*4);
                    short8 bl = *(const short8*)(pl + ks*16 + quad*4);
                    d = __builtin_amdgcn_mfma_f32_16x16x32_bf16(A[tap][ks][0], bh, d, 0,0,0);
                    d = __builtin_amdgcn_mfma_f32_16x16x32_bf16(A[tap][ks][0], bl, d, 0,0,0);
                    d = __builtin_amdgcn_mfma_f32_16x16x32_bf16(A[tap][ks][1], bh, d, 0,0,0);
                }
            }
            if (nt<4 || n<2){
                int rh = 16*nt + n;
                int hpos = l0 - 1 + rh;
                bool okh = (hpos>=0 && hpos<LSEQ);
                float h0 = okh? geluf(d[0]) : 0.f;
                float h1 = okh? geluf(d[1]) : 0.f;
                float h2 = okh? geluf(d[2]) : 0.f;
                float h3 = okh? geluf(d[3]) : 0.f;
                hTh[rh][q0]   = (unsigned)f2bf(h0) | ((unsigned)f2bf(h1)<<16);
                hTh[rh][q0+1] = (unsigned)f2bf(h2) | ((unsigned)f2bf(h3)<<16);
            }
        }
    }
    __syncthreads();

    // ---- conv2 (4 n-tiles, output pos l0..l0+63) + packed epilogue ----
    float esum=0.f;
    {
        const short* W2 = WB + (size_t)(lvl*2+1)*2*3*4096;
        short8 A[3][2][2];
        #pragma unroll
        for (int tap=0;tap<3;tap++)
            #pragma unroll
            for (int ks=0;ks<2;ks++)
                #pragma unroll
                for (int hl=0;hl<2;hl++)
                    A[tap][ks][hl] = *(const short8*)(W2 + (((size_t)hl*3+tap)*64 + (m0+n))*64 + ks*32 + quad*8);
        float bib[4], sc[4], bi2[4];
        #pragma unroll
        for (int reg=0;reg<4;reg++){
            int co = m0 + quad*4 + reg;
            bib[reg]=c2bB[lvl*64+co];
            sc[reg]=modscB[lvl*576+tslot*64+co];
            bi2[reg]=modbiB[lvl*576+tslot*64+co];
        }
        const float dt6 = dt/6.0f;
        const int qy0=(m0+quad*4)>>1;
        #pragma unroll
        for (int nt=0; nt<4; nt++){
            float4v d = {bib[0],bib[1],bib[2],bib[3]};
            #pragma unroll
            for (int tap=0;tap<3;tap++){
                const int rr = 16*nt + n + tap;
                const unsigned* ph=&hTh[rr][0];
                #pragma unroll
                for (int ks=0;ks<2;ks++){
                    short8 bh = *(const short8*)(ph + ks*16 + quad*4);
                    d = __builtin_amdgcn_mfma_f32_16x16x32_bf16(A[tap][ks][0], bh, d, 0,0,0);
                    d = __builtin_amdgcn_mfma_f32_16x16x32_bf16(A[tap][ks][1], bh, d, 0,0,0);
                }
            }
            int p = l0 + 16*nt + n;
            int ry = 16*nt + n + 2;
            unsigned uh0=yTh[ry][qy0],   ul0=yTl[ry][qy0];
            unsigned uh1=yTh[ry][qy0+1], ul1=yTl[ry][qy0+1];
            float yev[4];
            yev[0]=bf2f(uh0)+bf2f(ul0);
            yev[1]=bf2f(uh0>>16)+bf2f(ul0>>16);
            yev[2]=bf2f(uh1)+bf2f(ul1);
            yev[3]=bf2f(uh1>>16)+bf2f(ul1>>16);
            float kv[4];
            #pragma unroll
            for (int reg=0;reg<4;reg++){
                float m = d[reg]*sc[reg] + bi2[reg];
                kv[reg] = siluf(m) - 0.1f*yev[reg];
            }
            size_t ia = ((size_t)(b*32+qy0))*LSEQ + p;
            size_t ib = ia + LSEQ;
            if (eval==0){
                // acc == k1, deferred: eval1 reads acc from the k1 buffer
                kout[ia]=(unsigned)f2bf(kv[0])|((unsigned)f2bf(kv[1])<<16);
                kout[ib]=(unsigned)f2bf(kv[2])|((unsigned)f2bf(kv[3])<<16);
            } else if (eval<3){
                unsigned ka=(unsigned)f2bf(kv[0])|((unsigned)f2bf(kv[1])<<16);
                unsigned kb=(unsigned)f2bf(kv[2])|((unsigned)f2bf(kv[3])<<16);
                kout[ia]=ka; kout[ib]=kb;
                unsigned ua=accrd[ia], ub=accrd[ib];
                float a0=bf2f(ua)+2.f*kv[0],     a1=bf2f(ua>>16)+2.f*kv[1];
                float a2=bf2f(ub)+2.f*kv[2],     a3=bf2f(ub>>16)+2.f*kv[3];
                acc[ia]=(unsigned)f2bf(a0)|((unsigned)f2bf(a1)<<16);
                acc[ib]=(unsigned)f2bf(a2)|((unsigned)f2bf(a3)<<16);
            } else {
                unsigned ua=accrd[ia], ub=accrd[ib];
                float av[4]={bf2f(ua),bf2f(ua>>16),bf2f(ub),bf2f(ub>>16)};
                size_t gbase=(size_t)(b*64 + m0 + quad*4)*LSEQ + p;
                #pragma unroll
                for (int reg=0;reg<4;reg++){
                    size_t gi = gbase + (size_t)reg*LSEQ;
                    float yn = yin[gi] + dt6*(av[reg]+kv[reg]);
                    yout[gi]=yn;
                    esum += yn*yn;
                }
            }
        }
    }
    if (do_energy){
        for (int o=32;o>0;o>>=1) esum+=__shfl_down(esum,o,64);
        if ((tid&63)==0) red[tid>>6]=esum;
        __syncthreads();
        if (tid==0) atomicAdd(&eoutB[lvl*8+b], red[0]+red[1]+red[2]+red[3]);
    }
}

// -------- fused reconstruction: scale + [attn] + gate + residual ------------
// grid (32, NB). cur scaled by s(lvl_cur) on load (if lvl_cur>=0);
// detail read from det_in scaled by s(lvl_det); final detail written to det_out.
__global__ __launch_bounds__(256) void recon_kernel(
    const float* __restrict__ cur, const float* __restrict__ det_in,
    float* __restrict__ det_out,
    const float* __restrict__ a1w, const float* __restrict__ a1b,
    const float* __restrict__ a2w, const float* __restrict__ a2b,
    const float* __restrict__ gwt, const float* __restrict__ gb,
    float* __restrict__ curout,
    const float* __restrict__ ein, const float* __restrict__ eout,
    int lvl_cur, int lvl_det, int has_attn)
{
    __shared__ float yc[64][66];
    __shared__ float dtile[64][65];
    __shared__ float hid[16][64];
    const int tid=threadIdx.x, b=blockIdx.y, l0=blockIdx.x*64;
    float scur=1.f, sdet;
    if (lvl_cur>=0){
        float eo=eout[lvl_cur*8+b]*(1.0f/131072.0f);
        scur=sqrtf(ein[lvl_cur*8+b]/(eo+1e-8f));
    }
    {
        float eo=eout[lvl_det*8+b]*(1.0f/131072.0f);
        sdet=sqrtf(ein[lvl_det*8+b]/(eo+1e-8f));
    }
    for (int idx=tid; idx<64*66; idx+=256){
        int ci=idx/66, u=idx-ci*66;
        int l=l0+u-1;
        yc[ci][u]=(l>=0 && l<LSEQ)? scur*cur[(size_t)(b*64+ci)*LSEQ+l] : 0.f;
    }
    for (int idx=tid; idx<4096; idx+=256){
        int ci=idx>>6, p=idx&63;
        dtile[ci][p]=sdet*det_in[(size_t)(b*64+ci)*LSEQ+l0+p];
    }
    __syncthreads();
    if (has_attn){
        for (int idx=tid; idx<1024; idx+=256){
            int h=idx>>6, p=idx&63;
            float acc=a1b[h];
            const float* W=a1w+h*64;
            for (int ci=0;ci<64;ci++) acc += W[ci]*yc[ci][p+1];
            hid[h][p]=geluf(acc);
        }
        __syncthreads();
        for (int idx=tid; idx<4096; idx+=256){
            int co=idx>>6, p=idx&63;
            float acc=a2b[co];
            const float* W=a2w+co*16;
            #pragma unroll
            for (int h=0;h<16;h++) acc += W[h]*hid[h][p];
            float a=sigf(acc);
            float dnew = dtile[co][p]*(1.0f+a);
            dtile[co][p]=dnew;
            det_out[(size_t)(b*64+co)*LSEQ+l0+p]=dnew;
        }
        __syncthreads();
    } else {
        for (int idx=tid; idx<4096; idx+=256){
            int ci=idx>>6, p=idx&63;
            det_out[(size_t)(b*64+ci)*LSEQ+l0+p]=dtile[ci][p];
        }
    }
    const int co=tid&63, g=tid>>6;
    const int p0=g*16;
    float a[16];
    float bb=gb[co];
    #pragma unroll
    for (int i=0;i<16;i++) a[i]=bb;
    for (int ci=0;ci<64;ci++){
        float w0=gwt[(ci*3+0)*64+co];
        float w1_=gwt[(ci*3+1)*64+co];
        float w2_=gwt[(ci*3+2)*64+co];
        float x[18];
        #pragma unroll
        for (int j=0;j<18;j++) x[j]=yc[ci][p0+j];
        #pragma unroll
        for (int i=0;i<16;i++) a[i] += w0*x[i]+w1_*x[i+1]+w2_*x[i+2];
    }
    float r[16];
    #pragma unroll
    for (int i=0;i<16;i++){
        float gt=sigf(a[i]);
        r[i]=yc[co][p0+i+1]+gt*dtile[co][p0+i];
    }
    __syncthreads();
    #pragma unroll
    for (int i=0;i<16;i++) dtile[co][p0+i]=r[i];
    __syncthreads();
    for (int idx=tid; idx<4096; idx+=256){
        int ci=idx>>6, p=idx&63;
        curout[(size_t)(b*64+ci)*LSEQ+l0+p]=dtile[ci][p];
    }
}

extern "C" void kernel_launch(void* const* d_in, const int* in_sizes, int n_in,
                              void* d_out, int out_size, void* d_ws, size_t ws_size,
                              hipStream_t stream)
{
    (void)in_sizes; (void)n_in; (void)out_size; (void)ws_size;
    const float* x       =(const float*)d_in[0];
    const float* dy_w1   =(const float*)d_in[1];
    const float* dy_b1   =(const float*)d_in[2];
    const float* dy_wg1  =(const float*)d_in[3];
    const float* dy_bg1  =(const float*)d_in[4];
    const float* dy_wg2  =(const float*)d_in[5];
    const float* dy_bg2  =(const float*)d_in[6];
    const float* ode_c1w =(const float*)d_in[7];
    const float* ode_c1b =(const float*)d_in[8];
    const float* ode_c2w =(const float*)d_in[9];
    const float* ode_c2b =(const float*)d_in[10];
    const float* ode_wt  =(const float*)d_in[11];
    const float* ode_bt  =(const float*)d_in[12];
    const float* ode_wm  =(const float*)d_in[13];
    const float* ode_bm  =(const float*)d_in[14];
    const float* ode_emb =(const float*)d_in[15];
    const float* gate_w  =(const float*)d_in[16];
    const float* gate_b  =(const float*)d_in[17];
    const float* attn1_w =(const float*)d_in[18];
    const float* attn1_b =(const float*)d_in[19];
    const float* attn2_w =(const float*)d_in[20];
    const float* attn2_b =(const float*)d_in[21];
    float* out=(float*)d_out;
    float* ws=(float*)d_ws;
    const size_t N=NTOT;
    // workspace layout (floats)
    float* CB = ws;                      // coeff[4]: A0, D1, D2, D3 (4N)
    float* PB = ws+4*N;                  // y ping (4 levels) — also decomp temps
    float* QB = ws+8*N;                  // y pong (4 levels)
    unsigned* K0P=(unsigned*)(ws+12*N);  // packed-bf16 k ping (2N floats)
    unsigned* K1P=(unsigned*)(ws+14*N);  // packed-bf16 k pong
    unsigned* ACP=(unsigned*)(ws+16*N);  // packed-bf16 acc
    float* SM = ws+20*N;
    float* stat_ws =SM;          // 512
    float* lo_ws   =SM+512;      // 64
    float* hi_ws   =SM+576;      // 64
    float* rowstats=SM+1024;     // 4*512*8 = 16384
    float* ts_ws   =SM+17408;    // 4*8
    float* modsc   =SM+17536;    // 4*576
    float* modbi   =SM+19840;    // 4*576
    float* ein     =SM+22144;    // 32
    float* eoutb   =SM+22176;    // 32
    short* WB      =(short*)(SM+24576);  // 393216 bf16 = 196608 floats
    float* WTG     =SM+24576+196608;     // 3*12288 (gate weights, transposed)

    dim3 blk(256);

    wprep_kernel<<<768,blk,0,stream>>>(ode_c1w, ode_c2w, WB);
    for (int i=0;i<3;i++)
        wtrans_kernel<<<48,blk,0,stream>>>(gate_w+(size_t)i*12288, WTG+(size_t)i*12288);

    // ---- wavelet decomposition (3 levels, sequential; stat fused in filt) --
    stat_kernel<<<NROWS,blk,0,stream>>>(x, stat_ws);
    const float* cura=x;
    float* outsA[3]={PB, PB+N, CB};      // T0, T1, A0-final
    float* outsD[3]={CB+N, CB+2*N, CB+3*N};
    for (int lv=0; lv<3; lv++){
        dywan_kernel<<<1,blk,0,stream>>>(stat_ws, dy_w1,dy_b1,dy_wg1,dy_bg1,dy_wg2,dy_bg2,
                                         lo_ws, hi_ws, out+4*N);
        float* statn = (lv<2)? stat_ws : nullptr;
        filt_kernel<<<dim3(8,NROWS),blk,0,stream>>>(cura, lo_ws, hi_ws,
                                                    outsA[lv], outsD[lv], statn);
        cura=outsA[lv];
    }

    // ---- adaptive grids + modulation for all 4 levels ----
    tg_pass1<<<dim3(NROWS,4),blk,0,stream>>>(CB, rowstats);
    tg_finalize<<<4,blk,0,stream>>>(rowstats, ode_wt, ode_bt, ode_wm, ode_bm,
                                    ode_emb, ts_ws, modsc, modbi, ein, eoutb);

    // ---- RK4: 16 evals, each batched over 4 levels ----
    const float* yins[4]={CB, PB, QB, PB};
    float*       youts[4]={PB, QB, PB, QB};
    for (int step=0;step<4;step++){
        for (int ev=0;ev<4;ev++){
            const unsigned* kp=(ev==2)? K1P : K0P;
            unsigned* ko=(ev==1)? K1P : K0P;
            // acc source: eval1 reads acc from the k1 buffer (acc==k1 after
            // eval0); eval2/eval3 read the real acc buffer.
            const unsigned* ar=(ev==1)? K0P : ACP;
            int doe=(step==3 && ev==3)?1:0;
            ode_eval_all<<<dim3(32,NB,4),blk,0,stream>>>(
                yins[step],kp,ko,ar,ACP,youts[step],
                WB,ode_c1b,ode_c2b,modsc,modbi,ts_ws,eoutb,step,ev,doe);
        }
    }

    // ---- reconstruction (fused scale+attn+gate); evolved lives in QB ----
    // i=2: cur=s0*QB0, detail=s3*QB3 -> out3; current -> PB
    recon_kernel<<<dim3(32,NB),blk,0,stream>>>(QB+0*N, QB+3*N, out+3*N,
        attn1_w, attn1_b, attn2_w, attn2_b,
        WTG+2*12288, gate_b+128, PB, ein, eoutb, 0, 3, 0);
    // i=1: cur=PB, detail=s2*QB2 + attn(set1) -> out2; current -> QB(slot0)
    recon_kernel<<<dim3(32,NB),blk,0,stream>>>(PB, QB+2*N, out+2*N,
        attn1_w+1024, attn1_b+16, attn2_w+1024, attn2_b+64,
        WTG+1*12288, gate_b+64, QB, ein, eoutb, -1, 2, 1);
    // i=0: cur=QB(slot0), detail=s1*QB1 + attn(set0) -> out1; current -> out0
    recon_kernel<<<dim3(32,NB),blk,0,stream>>>(QB, QB+1*N, out+1*N,
        attn1_w, attn1_b, attn2_w, attn2_b,
        WTG, gate_b, out+0*N, ein, eoutb, -1, 1, 1);
}